// Round 2
// baseline (256.413 us; speedup 1.0000x reference)
//
#include <hip/hip_runtime.h>
#include <hip/hip_bf16.h>
#include <cstdint>
#include <cstddef>

// MHA fused pipeline, bf16 MFMA everywhere, fp32 accumulate.
// B=2 N=2048 E=1024 H=16 D=64; M = B*N = 4096; BH = 32.
// R1: attn LDS XOR-swizzle (rule-21 form: linear LDS dest, pre-swizzled global
//     source, swizzled reads; mask = (row>>1)&7 on the 16B-block index).

typedef __attribute__((ext_vector_type(8))) short short8;   // 8 bf16 (4 VGPR)
typedef __attribute__((ext_vector_type(4))) short short4v;
typedef __attribute__((ext_vector_type(4))) float f32x4;

#define MFMA16(a, b, c) __builtin_amdgcn_mfma_f32_16x16x32_bf16((a), (b), (c), 0, 0, 0)

__device__ __forceinline__ float b2f(short s) {
  union { unsigned u; float f; } x; x.u = ((unsigned)(unsigned short)s) << 16; return x.f;
}
__device__ __forceinline__ short f2b(float f) {  // RNE f32->bf16
  union { float f; unsigned u; } x; x.f = f;
  unsigned r = x.u + 0x7fffu + ((x.u >> 16) & 1u);
  return (short)(r >> 16);
}
__device__ __forceinline__ void async_lds16(const void* g, void* l) {
  __builtin_amdgcn_global_load_lds(
      (const __attribute__((address_space(1))) void*)g,
      (__attribute__((address_space(3))) void*)l, 16, 0, 0);
}

// ---------------- cast x (fp32 -> bf16), vectorized ----------------
__global__ __launch_bounds__(256) void cast_f32_bf16(const float* __restrict__ in,
                                                     short* __restrict__ out, int n4) {
  int idx = blockIdx.x * 256 + threadIdx.x;
  if (idx < n4) {
    f32x4 v = ((const f32x4*)in)[idx];
    short4v o;
    #pragma unroll
    for (int e = 0; e < 4; ++e) o[e] = f2b(v[e]);
    ((short4v*)out)[idx] = o;
  }
}

// ------------- transpose + cast: in [R][C] fp32 -> out [C][R] bf16 -------------
__global__ __launch_bounds__(256) void transpose_cast(const float* __restrict__ in,
                                                      short* __restrict__ out,
                                                      int R, int C) {
  __shared__ float tile[32][33];
  int c0 = blockIdx.x * 32, r0 = blockIdx.y * 32;
  int tx = threadIdx.x, ty = threadIdx.y;  // 32 x 8
  #pragma unroll
  for (int i = ty; i < 32; i += 8)
    tile[i][tx] = in[(size_t)(r0 + i) * C + c0 + tx];
  __syncthreads();
  #pragma unroll
  for (int i = ty; i < 32; i += 8)
    out[(size_t)(c0 + i) * R + r0 + tx] = f2b(tile[tx][i]);
}

// ---------------- GEMM1: qkv = xb @ wqkvT^T  + bias, scatter to Q/K/Vt ----------------
// A = xb [4096][1024] bf16 row-major; B^T = wT [3072][1024] bf16 row-major.
// Epilogue: col c -> which = c/1024 (uniform per block), h = (c%1024)/64, d = c%64.
//   Q,K: [bh][n][d]; V transposed: Vt [bh][d][n]  (so PV B-operand is k-contiguous).
__global__ __launch_bounds__(256) void gemm_qkv(const short* __restrict__ xb,
                                                const short* __restrict__ wT,
                                                const float* __restrict__ bias,
                                                short* __restrict__ Qb,
                                                short* __restrict__ Kb,
                                                short* __restrict__ Vt) {
  __shared__ short lds_a[128 * 32];
  __shared__ short lds_b[128 * 32];
  const int tid = threadIdx.x, wid = tid >> 6, lane = tid & 63;
  const int lg = lane >> 4, lr = lane & 15;
  const int m0 = blockIdx.x * 128, n0 = blockIdx.y * 128;
  const int wr = wid >> 1, wc = wid & 1;
  const int K = 1024;

  f32x4 acc[4][4];
  #pragma unroll
  for (int i = 0; i < 4; ++i)
    #pragma unroll
    for (int j = 0; j < 4; ++j) acc[i][j] = (f32x4)0.0f;

  for (int k0 = 0; k0 < K; k0 += 32) {
    #pragma unroll
    for (int it = 0; it < 2; ++it) {
      int chunk = it * 256 + tid;
      int row = chunk >> 2, kc = (chunk & 3) * 8;
      async_lds16(xb + (size_t)(m0 + row) * K + k0 + kc, lds_a + chunk * 8);
      async_lds16(wT + (size_t)(n0 + row) * K + k0 + kc, lds_b + chunk * 8);
    }
    __syncthreads();
    short8 af[4], bfr[4];
    #pragma unroll
    for (int i = 0; i < 4; ++i)
      af[i] = *(const short8*)&lds_a[(wr * 64 + i * 16 + lr) * 32 + lg * 8];
    #pragma unroll
    for (int j = 0; j < 4; ++j)
      bfr[j] = *(const short8*)&lds_b[(wc * 64 + j * 16 + lr) * 32 + lg * 8];
    #pragma unroll
    for (int i = 0; i < 4; ++i)
      #pragma unroll
      for (int j = 0; j < 4; ++j) acc[i][j] = MFMA16(af[i], bfr[j], acc[i][j]);
    __syncthreads();
  }

  // epilogue: C/D layout col = lane&15, row = (lane>>4)*4 + reg
  #pragma unroll
  for (int i = 0; i < 4; ++i) {
    int gm = m0 + wr * 64 + i * 16 + lg * 4;  // rows gm..gm+3 (same b: gm%4==0)
    int bb = gm >> 11, n = gm & 2047;
    #pragma unroll
    for (int j = 0; j < 4; ++j) {
      int gc = n0 + wc * 64 + j * 16 + lr;
      float bv = bias[gc];
      int which = gc >> 10;            // uniform per block (n0 % 128 == 0)
      int h = (gc >> 6) & 15;
      int dd = gc & 63;
      size_t qkbase = ((size_t)((bb * 16 + h) * 2048 + n)) * 64 + dd;
      size_t vtbase = ((size_t)((bb * 16 + h) * 64 + dd)) * 2048 + n;
      #pragma unroll
      for (int r = 0; r < 4; ++r) {
        short o = f2b(acc[i][j][r] + bv);
        if (which == 0)      Qb[qkbase + (size_t)r * 64] = o;
        else if (which == 1) Kb[qkbase + (size_t)r * 64] = o;
        else                 Vt[vtbase + r] = o;
      }
    }
  }
}

// ---------------- flash attention ----------------
// grid (32 bh, 16 q-tiles), 256 threads / 4 waves; wave owns 32 q-rows.
// KV tile = 64. K staged [64 j][64 d], Vt staged [64 d][64 n]. P via per-wave LDS.
// All three tiles XOR-swizzled: 16B-block index ^= (row>>1)&7.
//   K/V: linear LDS dest (global_load_lds) + pre-swizzled GLOBAL source + swz read.
//   P:   swz on both ds_write and ds_read.
__global__ __launch_bounds__(256) void attn_fwd(const short* __restrict__ Qb,
                                                const short* __restrict__ Kb,
                                                const short* __restrict__ Vt,
                                                short* __restrict__ aob) {
  __shared__ short k_lds[64 * 64];
  __shared__ short v_lds[64 * 64];
  __shared__ short p_lds[4 * 32 * 64];
  const int tid = threadIdx.x, wid = tid >> 6, lane = tid & 63;
  const int lg = lane >> 4, lr = lane & 15;
  const int bh = blockIdx.x, qt = blockIdx.y;
  const int q0 = qt * 128 + wid * 32;
  const short* Qbh = Qb + (size_t)bh * 2048 * 64;
  const short* Kbh = Kb + (size_t)bh * 2048 * 64;
  const short* Vbh = Vt + (size_t)bh * 64 * 2048;
  const int rm = (lr >> 1) & 7;   // read-side swizzle mask (row = *16 + lr)

  // Q fragments hoisted; fold in scale 1/sqrt(64) = 0.125 (exact pow2 in bf16)
  short8 qf[2][2];
  #pragma unroll
  for (int i = 0; i < 2; ++i)
    #pragma unroll
    for (int kk = 0; kk < 2; ++kk) {
      qf[i][kk] = *(const short8*)(Qbh + (size_t)(q0 + i * 16 + lr) * 64 + kk * 32 + lg * 8);
      #pragma unroll
      for (int e = 0; e < 8; ++e) qf[i][kk][e] = f2b(b2f(qf[i][kk][e]) * 0.125f);
    }

  f32x4 o[2][4];
  #pragma unroll
  for (int i = 0; i < 2; ++i)
    #pragma unroll
    for (int dt = 0; dt < 4; ++dt) o[i][dt] = (f32x4)0.0f;
  float m_[2][4], l_[2][4];
  #pragma unroll
  for (int i = 0; i < 2; ++i)
    #pragma unroll
    for (int r = 0; r < 4; ++r) { m_[i][r] = -__builtin_inff(); l_[i][r] = 0.0f; }

  for (int kv0 = 0; kv0 < 2048; kv0 += 64) {
    #pragma unroll
    for (int it = 0; it < 2; ++it) {
      int chunk = it * 256 + tid;
      int row = chunk >> 3;                       // [0,64)
      int src = ((chunk & 7) ^ ((row >> 1) & 7)) * 8;  // pre-swizzled source offset
      async_lds16(Kbh + (size_t)(kv0 + row) * 64 + src, k_lds + chunk * 8);
      async_lds16(Vbh + (size_t)row * 2048 + kv0 + src, v_lds + chunk * 8);
    }
    __syncthreads();

    // S = Q K^T : per wave [32][64]
    f32x4 s[2][4];
    #pragma unroll
    for (int i = 0; i < 2; ++i)
      #pragma unroll
      for (int jt = 0; jt < 4; ++jt) s[i][jt] = (f32x4)0.0f;
    #pragma unroll
    for (int jt = 0; jt < 4; ++jt)
      #pragma unroll
      for (int kk = 0; kk < 2; ++kk) {
        short8 kf = *(const short8*)&k_lds[(jt * 16 + lr) * 64 +
                                           (((kk * 4 + lg) ^ rm) * 8)];
        #pragma unroll
        for (int i = 0; i < 2; ++i) s[i][jt] = MFMA16(qf[i][kk], kf, s[i][jt]);
      }

    // online softmax; row = (lane>>4)*4 + r, col = jt*16 + (lane&15)
    float c_[2][4];
    #pragma unroll
    for (int i = 0; i < 2; ++i)
      #pragma unroll
      for (int r = 0; r < 4; ++r) {
        float mx = fmaxf(fmaxf(s[i][0][r], s[i][1][r]), fmaxf(s[i][2][r], s[i][3][r]));
        #pragma unroll
        for (int off = 1; off < 16; off <<= 1) mx = fmaxf(mx, __shfl_xor(mx, off));
        float mn = fmaxf(m_[i][r], mx);
        float corr = __expf(m_[i][r] - mn);
        m_[i][r] = mn;
        float ps = 0.0f;
        #pragma unroll
        for (int jt = 0; jt < 4; ++jt) {
          float p = __expf(s[i][jt][r] - mn);
          s[i][jt][r] = p;
          ps += p;
        }
        #pragma unroll
        for (int off = 1; off < 16; off <<= 1) ps += __shfl_xor(ps, off);
        l_[i][r] = l_[i][r] * corr + ps;
        c_[i][r] = corr;
      }
    #pragma unroll
    for (int i = 0; i < 2; ++i)
      #pragma unroll
      for (int dt = 0; dt < 4; ++dt)
        #pragma unroll
        for (int r = 0; r < 4; ++r) o[i][dt][r] *= c_[i][r];

    // P -> per-wave LDS (bf16, swizzled write), then PV
    #pragma unroll
    for (int i = 0; i < 2; ++i)
      #pragma unroll
      for (int r = 0; r < 4; ++r) {
        int prow = i * 16 + lg * 4 + r;
        int wmask = ((prow >> 1) & 7) << 3;
        #pragma unroll
        for (int jt = 0; jt < 4; ++jt)
          p_lds[wid * 2048 + prow * 64 + ((jt * 16 + lr) ^ wmask)] = f2b(s[i][jt][r]);
      }
    asm volatile("s_waitcnt lgkmcnt(0)" ::: "memory");
    __builtin_amdgcn_sched_barrier(0);

    #pragma unroll
    for (int kk = 0; kk < 2; ++kk) {
      short8 pa[2];
      #pragma unroll
      for (int i = 0; i < 2; ++i)
        pa[i] = *(const short8*)&p_lds[wid * 2048 + (i * 16 + lr) * 64 +
                                       (((kk * 4 + lg) ^ rm) * 8)];
      #pragma unroll
      for (int dt = 0; dt < 4; ++dt) {
        short8 vb = *(const short8*)&v_lds[(dt * 16 + lr) * 64 +
                                           (((kk * 4 + lg) ^ rm) * 8)];
        #pragma unroll
        for (int i = 0; i < 2; ++i) o[i][dt] = MFMA16(pa[i], vb, o[i][dt]);
      }
    }
    __syncthreads();
  }

  // epilogue: out layout [b][n][h*64+d] bf16
  const int bb = bh >> 4, h = bh & 15;
  #pragma unroll
  for (int i = 0; i < 2; ++i)
    #pragma unroll
    for (int dt = 0; dt < 4; ++dt)
      #pragma unroll
      for (int r = 0; r < 4; ++r) {
        int n = q0 + i * 16 + lg * 4 + r;
        float v = o[i][dt][r] / l_[i][r];
        aob[(size_t)(bb * 2048 + n) * 1024 + h * 64 + dt * 16 + lr] = f2b(v);
      }
}

// ---------------- GEMM2: out = aob @ wprojT^T + b_proj (fp32 out) ----------------
__global__ __launch_bounds__(256) void gemm_proj(const short* __restrict__ aob,
                                                 const short* __restrict__ wT,
                                                 const float* __restrict__ bias,
                                                 float* __restrict__ out) {
  __shared__ short lds_a[128 * 32];
  __shared__ short lds_b[128 * 32];
  const int tid = threadIdx.x, wid = tid >> 6, lane = tid & 63;
  const int lg = lane >> 4, lr = lane & 15;
  const int m0 = blockIdx.x * 128, n0 = blockIdx.y * 128;
  const int wr = wid >> 1, wc = wid & 1;
  const int K = 1024;

  f32x4 acc[4][4];
  #pragma unroll
  for (int i = 0; i < 4; ++i)
    #pragma unroll
    for (int j = 0; j < 4; ++j) acc[i][j] = (f32x4)0.0f;

  for (int k0 = 0; k0 < K; k0 += 32) {
    #pragma unroll
    for (int it = 0; it < 2; ++it) {
      int chunk = it * 256 + tid;
      int row = chunk >> 2, kc = (chunk & 3) * 8;
      async_lds16(aob + (size_t)(m0 + row) * K + k0 + kc, lds_a + chunk * 8);
      async_lds16(wT + (size_t)(n0 + row) * K + k0 + kc, lds_b + chunk * 8);
    }
    __syncthreads();
    short8 af[4], bfr[4];
    #pragma unroll
    for (int i = 0; i < 4; ++i)
      af[i] = *(const short8*)&lds_a[(wr * 64 + i * 16 + lr) * 32 + lg * 8];
    #pragma unroll
    for (int j = 0; j < 4; ++j)
      bfr[j] = *(const short8*)&lds_b[(wc * 64 + j * 16 + lr) * 32 + lg * 8];
    #pragma unroll
    for (int i = 0; i < 4; ++i)
      #pragma unroll
      for (int j = 0; j < 4; ++j) acc[i][j] = MFMA16(af[i], bfr[j], acc[i][j]);
    __syncthreads();
  }

  #pragma unroll
  for (int i = 0; i < 4; ++i) {
    int gm = m0 + wr * 64 + i * 16 + lg * 4;
    #pragma unroll
    for (int j = 0; j < 4; ++j) {
      int gc = n0 + wc * 64 + j * 16 + lr;
      float bv = bias[gc];
      #pragma unroll
      for (int r = 0; r < 4; ++r)
        out[(size_t)(gm + r) * 1024 + gc] = acc[i][j][r] + bv;
    }
  }
}

// ---------------- launcher ----------------
extern "C" void kernel_launch(void* const* d_in, const int* in_sizes, int n_in,
                              void* d_out, int out_size, void* d_ws, size_t ws_size,
                              hipStream_t stream) {
  const float* x     = (const float*)d_in[0];  // [2,2048,1024]
  const float* wqkv  = (const float*)d_in[1];  // [1024,3072]
  const float* bqkv  = (const float*)d_in[2];  // [3072]
  const float* wproj = (const float*)d_in[3];  // [1024,1024]
  const float* bproj = (const float*)d_in[4];  // [1024]
  float* out = (float*)d_out;

  char* ws = (char*)d_ws;
  short* xb     = (short*)ws; ws += (size_t)4096 * 1024 * 2;  // 8 MB
  short* wqkvT  = (short*)ws; ws += (size_t)3072 * 1024 * 2;  // 6 MB
  short* wprojT = (short*)ws; ws += (size_t)1024 * 1024 * 2;  // 2 MB
  short* Qb     = (short*)ws; ws += (size_t)32 * 2048 * 64 * 2;  // 8 MB
  short* Kb     = (short*)ws; ws += (size_t)32 * 2048 * 64 * 2;  // 8 MB
  short* Vt     = (short*)ws; ws += (size_t)32 * 64 * 2048 * 2;  // 8 MB
  short* aob    = (short*)ws; ws += (size_t)4096 * 1024 * 2;     // 8 MB
  // total 48 MB workspace

  cast_f32_bf16<<<4096, 256, 0, stream>>>(x, xb, 4096 * 1024 / 4);
  transpose_cast<<<dim3(96, 32), dim3(32, 8), 0, stream>>>(wqkv, wqkvT, 1024, 3072);
  transpose_cast<<<dim3(32, 32), dim3(32, 8), 0, stream>>>(wproj, wprojT, 1024, 1024);
  gemm_qkv<<<dim3(32, 24), 256, 0, stream>>>(xb, wqkvT, bqkv, Qb, Kb, Vt);
  attn_fwd<<<dim3(32, 16), 256, 0, stream>>>(Qb, Kb, Vt, aob);
  gemm_proj<<<dim3(32, 8), 256, 0, stream>>>(aob, wprojT, bproj, out);
}

// Round 3
// 221.825 us; speedup vs baseline: 1.1559x; 1.1559x over previous
//
#include <hip/hip_runtime.h>
#include <hip/hip_bf16.h>
#include <cstdint>
#include <cstddef>

// MHA fused pipeline, bf16 MFMA everywhere, fp32 accumulate.
// B=2 N=2048 E=1024 H=16 D=64; M = B*N = 4096; BH = 32.
// R1: attn LDS XOR-swizzle (verified: SQ_LDS_BANK_CONFLICT=0).
// R2: swapped QK^T (S^T = mfma(K,Q)) -> lane-local softmax rows:
//     64 shuffles/tile -> 8, scalar m/l/corr per lane, packed P (b64) and
//     packed output stores; 8 waves/block (512 thr) for 2x occupancy.

typedef __attribute__((ext_vector_type(8))) short short8;   // 8 bf16 (4 VGPR)
typedef __attribute__((ext_vector_type(4))) short short4v;
typedef __attribute__((ext_vector_type(4))) float f32x4;

#define MFMA16(a, b, c) __builtin_amdgcn_mfma_f32_16x16x32_bf16((a), (b), (c), 0, 0, 0)

__device__ __forceinline__ float b2f(short s) {
  union { unsigned u; float f; } x; x.u = ((unsigned)(unsigned short)s) << 16; return x.f;
}
__device__ __forceinline__ short f2b(float f) {  // RNE f32->bf16
  union { float f; unsigned u; } x; x.f = f;
  unsigned r = x.u + 0x7fffu + ((x.u >> 16) & 1u);
  return (short)(r >> 16);
}
__device__ __forceinline__ void async_lds16(const void* g, void* l) {
  __builtin_amdgcn_global_load_lds(
      (const __attribute__((address_space(1))) void*)g,
      (__attribute__((address_space(3))) void*)l, 16, 0, 0);
}

// ---------------- cast x (fp32 -> bf16), vectorized ----------------
__global__ __launch_bounds__(256) void cast_f32_bf16(const float* __restrict__ in,
                                                     short* __restrict__ out, int n4) {
  int idx = blockIdx.x * 256 + threadIdx.x;
  if (idx < n4) {
    f32x4 v = ((const f32x4*)in)[idx];
    short4v o;
    #pragma unroll
    for (int e = 0; e < 4; ++e) o[e] = f2b(v[e]);
    ((short4v*)out)[idx] = o;
  }
}

// ------------- transpose + cast: in [R][C] fp32 -> out [C][R] bf16 -------------
__global__ __launch_bounds__(256) void transpose_cast(const float* __restrict__ in,
                                                      short* __restrict__ out,
                                                      int R, int C) {
  __shared__ float tile[32][33];
  int c0 = blockIdx.x * 32, r0 = blockIdx.y * 32;
  int tx = threadIdx.x, ty = threadIdx.y;  // 32 x 8
  #pragma unroll
  for (int i = ty; i < 32; i += 8)
    tile[i][tx] = in[(size_t)(r0 + i) * C + c0 + tx];
  __syncthreads();
  #pragma unroll
  for (int i = ty; i < 32; i += 8)
    out[(size_t)(c0 + i) * R + r0 + tx] = f2b(tile[tx][i]);
}

// ---------------- GEMM1: qkv = xb @ wqkvT^T  + bias, scatter to Q/K/Vt ----------------
__global__ __launch_bounds__(256) void gemm_qkv(const short* __restrict__ xb,
                                                const short* __restrict__ wT,
                                                const float* __restrict__ bias,
                                                short* __restrict__ Qb,
                                                short* __restrict__ Kb,
                                                short* __restrict__ Vt) {
  __shared__ short lds_a[128 * 32];
  __shared__ short lds_b[128 * 32];
  const int tid = threadIdx.x, wid = tid >> 6, lane = tid & 63;
  const int lg = lane >> 4, lr = lane & 15;
  const int m0 = blockIdx.x * 128, n0 = blockIdx.y * 128;
  const int wr = wid >> 1, wc = wid & 1;
  const int K = 1024;

  f32x4 acc[4][4];
  #pragma unroll
  for (int i = 0; i < 4; ++i)
    #pragma unroll
    for (int j = 0; j < 4; ++j) acc[i][j] = (f32x4)0.0f;

  for (int k0 = 0; k0 < K; k0 += 32) {
    #pragma unroll
    for (int it = 0; it < 2; ++it) {
      int chunk = it * 256 + tid;
      int row = chunk >> 2, kc = (chunk & 3) * 8;
      async_lds16(xb + (size_t)(m0 + row) * K + k0 + kc, lds_a + chunk * 8);
      async_lds16(wT + (size_t)(n0 + row) * K + k0 + kc, lds_b + chunk * 8);
    }
    __syncthreads();
    short8 af[4], bfr[4];
    #pragma unroll
    for (int i = 0; i < 4; ++i)
      af[i] = *(const short8*)&lds_a[(wr * 64 + i * 16 + lr) * 32 + lg * 8];
    #pragma unroll
    for (int j = 0; j < 4; ++j)
      bfr[j] = *(const short8*)&lds_b[(wc * 64 + j * 16 + lr) * 32 + lg * 8];
    #pragma unroll
    for (int i = 0; i < 4; ++i)
      #pragma unroll
      for (int j = 0; j < 4; ++j) acc[i][j] = MFMA16(af[i], bfr[j], acc[i][j]);
    __syncthreads();
  }

  // epilogue: C/D layout col = lane&15, row = (lane>>4)*4 + reg
  #pragma unroll
  for (int i = 0; i < 4; ++i) {
    int gm = m0 + wr * 64 + i * 16 + lg * 4;  // rows gm..gm+3 (same b: gm%4==0)
    int bb = gm >> 11, n = gm & 2047;
    #pragma unroll
    for (int j = 0; j < 4; ++j) {
      int gc = n0 + wc * 64 + j * 16 + lr;
      float bv = bias[gc];
      int which = gc >> 10;            // uniform per block (n0 % 128 == 0)
      int h = (gc >> 6) & 15;
      int dd = gc & 63;
      size_t qkbase = ((size_t)((bb * 16 + h) * 2048 + n)) * 64 + dd;
      if (which == 2) {                // Vt: r contiguous along n -> pack 8B
        size_t vtbase = ((size_t)((bb * 16 + h) * 64 + dd)) * 2048 + n;
        short4v pv;
        #pragma unroll
        for (int r = 0; r < 4; ++r) pv[r] = f2b(acc[i][j][r] + bv);
        *(short4v*)&Vt[vtbase] = pv;
      } else {
        short* dst = (which == 0) ? Qb : Kb;
        #pragma unroll
        for (int r = 0; r < 4; ++r)
          dst[qkbase + (size_t)r * 64] = f2b(acc[i][j][r] + bv);
      }
    }
  }
}

// ---------------- flash attention (swapped-operand form) ----------------
// grid (32 bh, 16 q-tiles), 512 threads / 8 waves; wave owns 16 q-rows (q = q0+lr).
// KV tile = 64. K staged [64 k][64 d], Vt staged [64 d][64 n]; XOR-swizzled
// (16B-block idx ^= (row>>1)&7; linear LDS dest + pre-swizzled global source).
// S^T = mfma(K,Q): lane holds S[q=lr][k=jt*16+lg*4+r] -> softmax rows lane-local.
// O^T = mfma(Vt,P): lane holds O[q=lr][d=dt*16+lg*4+r].
__global__ __launch_bounds__(512) void attn_fwd(const short* __restrict__ Qb,
                                                const short* __restrict__ Kb,
                                                const short* __restrict__ Vt,
                                                short* __restrict__ aob) {
  __shared__ short k_lds[64 * 64];
  __shared__ short v_lds[64 * 64];
  __shared__ short p_lds[8 * 16 * 64];
  const int tid = threadIdx.x, wid = tid >> 6, lane = tid & 63;
  const int lg = lane >> 4, lr = lane & 15;
  const int bh = blockIdx.x, qt = blockIdx.y;
  const int q0 = qt * 128 + wid * 16;
  const short* Qbh = Qb + (size_t)bh * 2048 * 64;
  const short* Kbh = Kb + (size_t)bh * 2048 * 64;
  const short* Vbh = Vt + (size_t)bh * 64 * 2048;
  const int rm = (lr >> 1) & 7;   // read-side swizzle mask (rows indexed by lr)

  // Q fragments hoisted; fold in scale 1/sqrt(64) = 0.125 (exact pow2 in bf16)
  short8 qf[2];
  #pragma unroll
  for (int kk = 0; kk < 2; ++kk) {
    qf[kk] = *(const short8*)(Qbh + (size_t)(q0 + lr) * 64 + kk * 32 + lg * 8);
    #pragma unroll
    for (int e = 0; e < 8; ++e) qf[kk][e] = f2b(b2f(qf[kk][e]) * 0.125f);
  }

  f32x4 o[4];
  #pragma unroll
  for (int dt = 0; dt < 4; ++dt) o[dt] = (f32x4)0.0f;
  float m_ = -__builtin_inff(), l_ = 0.0f;

  for (int kv0 = 0; kv0 < 2048; kv0 += 64) {
    {
      int row = tid >> 3;                             // [0,64)
      int src = ((tid & 7) ^ ((row >> 1) & 7)) * 8;   // pre-swizzled source offset
      async_lds16(Kbh + (size_t)(kv0 + row) * 64 + src, k_lds + tid * 8);
      async_lds16(Vbh + (size_t)row * 2048 + kv0 + src, v_lds + tid * 8);
    }
    __syncthreads();

    // S^T = K Q^T : per wave [64 k][16 q]; s[jt][r] = S[q=lr][k=jt*16+lg*4+r]
    f32x4 s[4];
    #pragma unroll
    for (int jt = 0; jt < 4; ++jt) s[jt] = (f32x4)0.0f;
    #pragma unroll
    for (int jt = 0; jt < 4; ++jt)
      #pragma unroll
      for (int kk = 0; kk < 2; ++kk) {
        short8 kf = *(const short8*)&k_lds[(jt * 16 + lr) * 64 +
                                           (((kk * 4 + lg) ^ rm) * 8)];
        s[jt] = MFMA16(kf, qf[kk], s[jt]);
      }

    // online softmax: row q=lr is lane-local (16 vals) + lanes {lr,lr+16,+32,+48}
    float mx = s[0][0];
    #pragma unroll
    for (int jt = 0; jt < 4; ++jt)
      #pragma unroll
      for (int r = 0; r < 4; ++r) mx = fmaxf(mx, s[jt][r]);
    mx = fmaxf(mx, __shfl_xor(mx, 16));
    mx = fmaxf(mx, __shfl_xor(mx, 32));
    float mn = fmaxf(m_, mx);
    float corr = __expf(m_ - mn);
    m_ = mn;
    float ps = 0.0f;
    #pragma unroll
    for (int jt = 0; jt < 4; ++jt)
      #pragma unroll
      for (int r = 0; r < 4; ++r) {
        float p = __expf(s[jt][r] - mn);
        s[jt][r] = p;
        ps += p;
      }
    ps += __shfl_xor(ps, 16);
    ps += __shfl_xor(ps, 32);
    l_ = l_ * corr + ps;
    #pragma unroll
    for (int dt = 0; dt < 4; ++dt)
      #pragma unroll
      for (int r = 0; r < 4; ++r) o[dt][r] *= corr;

    // P -> per-wave LDS [16 q][64 k], swizzled, packed b64 writes
    #pragma unroll
    for (int jt = 0; jt < 4; ++jt) {
      short4v pv;
      #pragma unroll
      for (int r = 0; r < 4; ++r) pv[r] = f2b(s[jt][r]);
      // k = jt*16 + lg*4 + r: 16B-block = jt*2 + (lg>>1), 8B half = lg&1
      *(short4v*)&p_lds[wid * 1024 + lr * 64 +
                        (((jt * 2 + (lg >> 1)) ^ rm) * 8) + (lg & 1) * 4] = pv;
    }
    asm volatile("s_waitcnt lgkmcnt(0)" ::: "memory");
    __builtin_amdgcn_sched_barrier(0);

    // O^T += V^T P^T : o[dt] covers d = dt*16+lg*4+r for q = lr
    #pragma unroll
    for (int kk = 0; kk < 2; ++kk) {
      short8 pa = *(const short8*)&p_lds[wid * 1024 + lr * 64 +
                                         (((kk * 4 + lg) ^ rm) * 8)];
      #pragma unroll
      for (int dt = 0; dt < 4; ++dt) {
        short8 vb = *(const short8*)&v_lds[(dt * 16 + lr) * 64 +
                                           (((kk * 4 + lg) ^ rm) * 8)];
        o[dt] = MFMA16(vb, pa, o[dt]);
      }
    }
    __syncthreads();
  }

  // epilogue: out layout [b][n][h*64+d] bf16; n = q0+lr, packed 8B stores
  const int bb = bh >> 4, h = bh & 15;
  const float inv_l = __frcp_rn(l_);
  #pragma unroll
  for (int dt = 0; dt < 4; ++dt) {
    short4v ov;
    #pragma unroll
    for (int r = 0; r < 4; ++r) ov[r] = f2b(o[dt][r] * inv_l);
    *(short4v*)&aob[(size_t)(bb * 2048 + q0 + lr) * 1024 + h * 64 + dt * 16 + lg * 4] = ov;
  }
}

// ---------------- GEMM2: out = aob @ wprojT^T + b_proj (fp32 out) ----------------
__global__ __launch_bounds__(256) void gemm_proj(const short* __restrict__ aob,
                                                 const short* __restrict__ wT,
                                                 const float* __restrict__ bias,
                                                 float* __restrict__ out) {
  __shared__ short lds_a[128 * 32];
  __shared__ short lds_b[128 * 32];
  const int tid = threadIdx.x, wid = tid >> 6, lane = tid & 63;
  const int lg = lane >> 4, lr = lane & 15;
  const int m0 = blockIdx.x * 128, n0 = blockIdx.y * 128;
  const int wr = wid >> 1, wc = wid & 1;
  const int K = 1024;

  f32x4 acc[4][4];
  #pragma unroll
  for (int i = 0; i < 4; ++i)
    #pragma unroll
    for (int j = 0; j < 4; ++j) acc[i][j] = (f32x4)0.0f;

  for (int k0 = 0; k0 < K; k0 += 32) {
    #pragma unroll
    for (int it = 0; it < 2; ++it) {
      int chunk = it * 256 + tid;
      int row = chunk >> 2, kc = (chunk & 3) * 8;
      async_lds16(aob + (size_t)(m0 + row) * K + k0 + kc, lds_a + chunk * 8);
      async_lds16(wT + (size_t)(n0 + row) * K + k0 + kc, lds_b + chunk * 8);
    }
    __syncthreads();
    short8 af[4], bfr[4];
    #pragma unroll
    for (int i = 0; i < 4; ++i)
      af[i] = *(const short8*)&lds_a[(wr * 64 + i * 16 + lr) * 32 + lg * 8];
    #pragma unroll
    for (int j = 0; j < 4; ++j)
      bfr[j] = *(const short8*)&lds_b[(wc * 64 + j * 16 + lr) * 32 + lg * 8];
    #pragma unroll
    for (int i = 0; i < 4; ++i)
      #pragma unroll
      for (int j = 0; j < 4; ++j) acc[i][j] = MFMA16(af[i], bfr[j], acc[i][j]);
    __syncthreads();
  }

  #pragma unroll
  for (int i = 0; i < 4; ++i) {
    int gm = m0 + wr * 64 + i * 16 + lg * 4;
    #pragma unroll
    for (int j = 0; j < 4; ++j) {
      int gc = n0 + wc * 64 + j * 16 + lr;
      float bv = bias[gc];
      #pragma unroll
      for (int r = 0; r < 4; ++r)
        out[(size_t)(gm + r) * 1024 + gc] = acc[i][j][r] + bv;
    }
  }
}

// ---------------- launcher ----------------
extern "C" void kernel_launch(void* const* d_in, const int* in_sizes, int n_in,
                              void* d_out, int out_size, void* d_ws, size_t ws_size,
                              hipStream_t stream) {
  const float* x     = (const float*)d_in[0];  // [2,2048,1024]
  const float* wqkv  = (const float*)d_in[1];  // [1024,3072]
  const float* bqkv  = (const float*)d_in[2];  // [3072]
  const float* wproj = (const float*)d_in[3];  // [1024,1024]
  const float* bproj = (const float*)d_in[4];  // [1024]
  float* out = (float*)d_out;

  char* ws = (char*)d_ws;
  short* xb     = (short*)ws; ws += (size_t)4096 * 1024 * 2;  // 8 MB
  short* wqkvT  = (short*)ws; ws += (size_t)3072 * 1024 * 2;  // 6 MB
  short* wprojT = (short*)ws; ws += (size_t)1024 * 1024 * 2;  // 2 MB
  short* Qb     = (short*)ws; ws += (size_t)32 * 2048 * 64 * 2;  // 8 MB
  short* Kb     = (short*)ws; ws += (size_t)32 * 2048 * 64 * 2;  // 8 MB
  short* Vt     = (short*)ws; ws += (size_t)32 * 64 * 2048 * 2;  // 8 MB
  short* aob    = (short*)ws; ws += (size_t)4096 * 1024 * 2;     // 8 MB
  // total 48 MB workspace

  cast_f32_bf16<<<4096, 256, 0, stream>>>(x, xb, 4096 * 1024 / 4);
  transpose_cast<<<dim3(96, 32), dim3(32, 8), 0, stream>>>(wqkv, wqkvT, 1024, 3072);
  transpose_cast<<<dim3(32, 32), dim3(32, 8), 0, stream>>>(wproj, wprojT, 1024, 1024);
  gemm_qkv<<<dim3(32, 24), 256, 0, stream>>>(xb, wqkvT, bqkv, Qb, Kb, Vt);
  attn_fwd<<<dim3(32, 16), 512, 0, stream>>>(Qb, Kb, Vt, aob);
  gemm_proj<<<dim3(32, 8), 256, 0, stream>>>(aob, wprojT, bproj, out);
}

// Round 5
// 214.470 us; speedup vs baseline: 1.1956x; 1.0343x over previous
//
#include <hip/hip_runtime.h>
#include <hip/hip_bf16.h>
#include <cstdint>
#include <cstddef>

// MHA fused pipeline, bf16 MFMA everywhere, fp32 accumulate.
// B=2 N=2048 E=1024 H=16 D=64; M = B*N = 4096; BH = 32.
// R1: attn LDS XOR-swizzle (verified: SQ_LDS_BANK_CONFLICT=0).
// R2: swapped QK^T -> lane-local softmax (122 -> 76 us, MfmaUtil 11 -> 18).
// R4: attn K/V double-buffer prefetch (T3-minimum), exp2-domain softmax,
//     defer-max (T13), XCD chunked swizzles, gemm_proj retile 64x128 (2 blk/CU).
// R5: fix compile — __exp2f -> __builtin_amdgcn_exp2f (v_exp_f32 is 2^x).

typedef __attribute__((ext_vector_type(8))) short short8;   // 8 bf16 (4 VGPR)
typedef __attribute__((ext_vector_type(4))) short short4v;
typedef __attribute__((ext_vector_type(4))) float f32x4;

#define MFMA16(a, b, c) __builtin_amdgcn_mfma_f32_16x16x32_bf16((a), (b), (c), 0, 0, 0)
#define EXP2F(x) __builtin_amdgcn_exp2f(x)

__device__ __forceinline__ float b2f(short s) {
  union { unsigned u; float f; } x; x.u = ((unsigned)(unsigned short)s) << 16; return x.f;
}
__device__ __forceinline__ short f2b(float f) {  // RNE f32->bf16
  union { float f; unsigned u; } x; x.f = f;
  unsigned r = x.u + 0x7fffu + ((x.u >> 16) & 1u);
  return (short)(r >> 16);
}
__device__ __forceinline__ void async_lds16(const void* g, void* l) {
  __builtin_amdgcn_global_load_lds(
      (const __attribute__((address_space(1))) void*)g,
      (__attribute__((address_space(3))) void*)l, 16, 0, 0);
}

// ---------------- cast x (fp32 -> bf16), vectorized ----------------
__global__ __launch_bounds__(256) void cast_f32_bf16(const float* __restrict__ in,
                                                     short* __restrict__ out, int n4) {
  int idx = blockIdx.x * 256 + threadIdx.x;
  if (idx < n4) {
    f32x4 v = ((const f32x4*)in)[idx];
    short4v o;
    #pragma unroll
    for (int e = 0; e < 4; ++e) o[e] = f2b(v[e]);
    ((short4v*)out)[idx] = o;
  }
}

// ------------- transpose + cast: in [R][C] fp32 -> out [C][R] bf16 -------------
__global__ __launch_bounds__(256) void transpose_cast(const float* __restrict__ in,
                                                      short* __restrict__ out,
                                                      int R, int C) {
  __shared__ float tile[32][33];
  int c0 = blockIdx.x * 32, r0 = blockIdx.y * 32;
  int tx = threadIdx.x, ty = threadIdx.y;  // 32 x 8
  #pragma unroll
  for (int i = ty; i < 32; i += 8)
    tile[i][tx] = in[(size_t)(r0 + i) * C + c0 + tx];
  __syncthreads();
  #pragma unroll
  for (int i = ty; i < 32; i += 8)
    out[(size_t)(c0 + i) * R + r0 + tx] = f2b(tile[tx][i]);
}

// ---------------- GEMM1: qkv = xb @ wqkvT^T  + bias, scatter to Q/K/Vt ----------------
// 1D grid 768 with chunked XCD swizzle (768 % 8 == 0 -> simple bijective form).
__global__ __launch_bounds__(256) void gemm_qkv(const short* __restrict__ xb,
                                                const short* __restrict__ wT,
                                                const float* __restrict__ bias,
                                                short* __restrict__ Qb,
                                                short* __restrict__ Kb,
                                                short* __restrict__ Vt) {
  __shared__ short lds_a[128 * 32];
  __shared__ short lds_b[128 * 32];
  const int tid = threadIdx.x, wid = tid >> 6, lane = tid & 63;
  const int lg = lane >> 4, lr = lane & 15;
  const int lin = blockIdx.x;
  const int swz = (lin & 7) * 96 + (lin >> 3);   // XCD k owns swz [k*96, (k+1)*96)
  const int m0 = (swz & 31) * 128, n0 = (swz >> 5) * 128;  // same-B-panel co-located
  const int wr = wid >> 1, wc = wid & 1;
  const int K = 1024;

  f32x4 acc[4][4];
  #pragma unroll
  for (int i = 0; i < 4; ++i)
    #pragma unroll
    for (int j = 0; j < 4; ++j) acc[i][j] = (f32x4)0.0f;

  for (int k0 = 0; k0 < K; k0 += 32) {
    #pragma unroll
    for (int it = 0; it < 2; ++it) {
      int chunk = it * 256 + tid;
      int row = chunk >> 2, kc = (chunk & 3) * 8;
      async_lds16(xb + (size_t)(m0 + row) * K + k0 + kc, lds_a + chunk * 8);
      async_lds16(wT + (size_t)(n0 + row) * K + k0 + kc, lds_b + chunk * 8);
    }
    __syncthreads();
    short8 af[4], bfr[4];
    #pragma unroll
    for (int i = 0; i < 4; ++i)
      af[i] = *(const short8*)&lds_a[(wr * 64 + i * 16 + lr) * 32 + lg * 8];
    #pragma unroll
    for (int j = 0; j < 4; ++j)
      bfr[j] = *(const short8*)&lds_b[(wc * 64 + j * 16 + lr) * 32 + lg * 8];
    #pragma unroll
    for (int i = 0; i < 4; ++i)
      #pragma unroll
      for (int j = 0; j < 4; ++j) acc[i][j] = MFMA16(af[i], bfr[j], acc[i][j]);
    __syncthreads();
  }

  // epilogue: C/D layout col = lane&15, row = (lane>>4)*4 + reg
  #pragma unroll
  for (int i = 0; i < 4; ++i) {
    int gm = m0 + wr * 64 + i * 16 + lg * 4;  // rows gm..gm+3 (same b: gm%4==0)
    int bb = gm >> 11, n = gm & 2047;
    #pragma unroll
    for (int j = 0; j < 4; ++j) {
      int gc = n0 + wc * 64 + j * 16 + lr;
      float bv = bias[gc];
      int which = gc >> 10;            // uniform per block (n0 % 128 == 0)
      int h = (gc >> 6) & 15;
      int dd = gc & 63;
      size_t qkbase = ((size_t)((bb * 16 + h) * 2048 + n)) * 64 + dd;
      if (which == 2) {                // Vt: r contiguous along n -> pack 8B
        size_t vtbase = ((size_t)((bb * 16 + h) * 64 + dd)) * 2048 + n;
        short4v pv;
        #pragma unroll
        for (int r = 0; r < 4; ++r) pv[r] = f2b(acc[i][j][r] + bv);
        *(short4v*)&Vt[vtbase] = pv;
      } else {
        short* dst = (which == 0) ? Qb : Kb;
        #pragma unroll
        for (int r = 0; r < 4; ++r)
          dst[qkbase + (size_t)r * 64] = f2b(acc[i][j][r] + bv);
      }
    }
  }
}

// ---------------- flash attention (swapped-operand, dbuf, exp2, defer-max) ----------------
// 1D grid 512 (chunked XCD swizzle, qt-major so same-bh blocks co-locate).
// 512 threads / 8 waves; wave owns 16 q-rows (q = q0+lr). KV tile = 64,
// double-buffered. S^T = mfma(K,Q): lane holds S[q=lr][k=jt*16+lg*4+r].
// Scores in log2 domain (Q pre-scaled by 0.125*log2e); defer-max THR=8.
__global__ __launch_bounds__(512) void attn_fwd(const short* __restrict__ Qb,
                                                const short* __restrict__ Kb,
                                                const short* __restrict__ Vt,
                                                short* __restrict__ aob) {
  __shared__ short k_lds[2][64 * 64];
  __shared__ short v_lds[2][64 * 64];
  __shared__ short p_lds[8 * 16 * 64];
  const int tid = threadIdx.x, wid = tid >> 6, lane = tid & 63;
  const int lg = lane >> 4, lr = lane & 15;
  const int lin = blockIdx.x;
  const int swz = (lin & 7) * 64 + (lin >> 3);
  const int qt = swz & 15, bh = swz >> 4;   // XCD k owns bh [k*4, k*4+4)
  const int q0 = qt * 128 + wid * 16;
  const short* Qbh = Qb + (size_t)bh * 2048 * 64;
  const short* Kbh = Kb + (size_t)bh * 2048 * 64;
  const short* Vbh = Vt + (size_t)bh * 64 * 2048;
  const int rm = (lr >> 1) & 7;   // read-side swizzle mask (rows indexed by lr)

  // stage one KV tile (linear LDS dest + pre-swizzled global source)
  const int srow = tid >> 3;
  const int ssrc = ((tid & 7) ^ ((srow >> 1) & 7)) * 8;

  // Q fragments hoisted; fold scale 0.125 * log2(e) (exp2-domain scores)
  short8 qf[2];
  #pragma unroll
  for (int kk = 0; kk < 2; ++kk) {
    qf[kk] = *(const short8*)(Qbh + (size_t)(q0 + lr) * 64 + kk * 32 + lg * 8);
    #pragma unroll
    for (int e = 0; e < 8; ++e) qf[kk][e] = f2b(b2f(qf[kk][e]) * 0.1803368801f);
  }

  f32x4 o[4];
  #pragma unroll
  for (int dt = 0; dt < 4; ++dt) o[dt] = (f32x4)0.0f;
  float m_ = -__builtin_inff(), l_ = 0.0f;

  // prologue: stage tile 0 into buf 0
  async_lds16(Kbh + (size_t)srow * 64 + ssrc, &k_lds[0][tid * 8]);
  async_lds16(Vbh + (size_t)srow * 2048 + 0 + ssrc, &v_lds[0][tid * 8]);
  asm volatile("s_waitcnt vmcnt(0)" ::: "memory");
  __syncthreads();

  for (int t = 0; t < 32; ++t) {
    const int cur = t & 1;
    // prefetch next tile into buf^1 (latency hides under this tile's compute)
    if (t + 1 < 32) {
      int kvn = (t + 1) * 64;
      async_lds16(Kbh + (size_t)(kvn + srow) * 64 + ssrc, &k_lds[cur ^ 1][tid * 8]);
      async_lds16(Vbh + (size_t)srow * 2048 + kvn + ssrc, &v_lds[cur ^ 1][tid * 8]);
    }

    // S^T = K Q^T : s[jt][r] = S[q=lr][k=jt*16+lg*4+r], log2 domain
    f32x4 s[4];
    #pragma unroll
    for (int jt = 0; jt < 4; ++jt) s[jt] = (f32x4)0.0f;
    #pragma unroll
    for (int jt = 0; jt < 4; ++jt)
      #pragma unroll
      for (int kk = 0; kk < 2; ++kk) {
        short8 kf = *(const short8*)&k_lds[cur][(jt * 16 + lr) * 64 +
                                               (((kk * 4 + lg) ^ rm) * 8)];
        s[jt] = MFMA16(kf, qf[kk], s[jt]);
      }

    // online softmax, lane-local row + lanes {lr, lr+16, lr+32, lr+48}
    float pmax = s[0][0];
    #pragma unroll
    for (int jt = 0; jt < 4; ++jt)
      #pragma unroll
      for (int r = 0; r < 4; ++r) pmax = fmaxf(pmax, s[jt][r]);
    pmax = fmaxf(pmax, __shfl_xor(pmax, 16));
    pmax = fmaxf(pmax, __shfl_xor(pmax, 32));
    if (!__all(pmax - m_ <= 8.0f)) {      // defer-max: skip rescale if growth small
      float mn = fmaxf(m_, pmax);
      float corr = EXP2F(m_ - mn);        // exp2(-inf) = 0 handles t=0
      m_ = mn;
      l_ *= corr;
      #pragma unroll
      for (int dt = 0; dt < 4; ++dt)
        #pragma unroll
        for (int r = 0; r < 4; ++r) o[dt][r] *= corr;
    }
    float ps = 0.0f;
    #pragma unroll
    for (int jt = 0; jt < 4; ++jt)
      #pragma unroll
      for (int r = 0; r < 4; ++r) {
        float p = EXP2F(s[jt][r] - m_);     // bounded by 2^8 when deferred
        s[jt][r] = p;
        ps += p;
      }
    ps += __shfl_xor(ps, 16);
    ps += __shfl_xor(ps, 32);
    l_ += ps;

    // P -> per-wave LDS [16 q][64 k], swizzled, packed b64 writes
    #pragma unroll
    for (int jt = 0; jt < 4; ++jt) {
      short4v pv;
      #pragma unroll
      for (int r = 0; r < 4; ++r) pv[r] = f2b(s[jt][r]);
      *(short4v*)&p_lds[wid * 1024 + lr * 64 +
                        (((jt * 2 + (lg >> 1)) ^ rm) * 8) + (lg & 1) * 4] = pv;
    }
    asm volatile("s_waitcnt lgkmcnt(0)" ::: "memory");
    __builtin_amdgcn_sched_barrier(0);

    // O^T += V^T P^T : o[dt] covers d = dt*16+lg*4+r for q = lr
    #pragma unroll
    for (int kk = 0; kk < 2; ++kk) {
      short8 pa = *(const short8*)&p_lds[wid * 1024 + lr * 64 +
                                         (((kk * 4 + lg) ^ rm) * 8)];
      #pragma unroll
      for (int dt = 0; dt < 4; ++dt) {
        short8 vb = *(const short8*)&v_lds[cur][(dt * 16 + lr) * 64 +
                                               (((kk * 4 + lg) ^ rm) * 8)];
        o[dt] = MFMA16(vb, pa, o[dt]);
      }
    }
    // single drain+barrier per tile (prefetch was issued ~2000 cyc ago)
    asm volatile("s_waitcnt vmcnt(0)" ::: "memory");
    __syncthreads();
  }

  // epilogue: out layout [b][n][h*64+d] bf16; n = q0+lr, packed 8B stores
  const int bb = bh >> 4, h = bh & 15;
  const float inv_l = __frcp_rn(l_);
  #pragma unroll
  for (int dt = 0; dt < 4; ++dt) {
    short4v ov;
    #pragma unroll
    for (int r = 0; r < 4; ++r) ov[r] = f2b(o[dt][r] * inv_l);
    *(short4v*)&aob[(size_t)(bb * 2048 + q0 + lr) * 1024 + h * 64 + dt * 16 + lg * 4] = ov;
  }
}

// ---------------- GEMM2: out = aob @ wprojT^T + b_proj (fp32 out) ----------------
// R4: 64x128 tile, 1D grid 512 (2 blocks/CU for latency hiding), XCD swizzle.
// 4 waves: wave (mw = wid>>1, nw = wid&1) owns rows mw*32+[0,32), cols nw*64+[0,64).
__global__ __launch_bounds__(256) void gemm_proj(const short* __restrict__ aob,
                                                 const short* __restrict__ wT,
                                                 const float* __restrict__ bias,
                                                 float* __restrict__ out) {
  __shared__ short lds_a[64 * 32];
  __shared__ short lds_b[128 * 32];
  const int tid = threadIdx.x, wid = tid >> 6, lane = tid & 63;
  const int lg = lane >> 4, lr = lane & 15;
  const int lin = blockIdx.x;
  const int swz = (lin & 7) * 64 + (lin >> 3);
  const int m0 = (swz & 63) * 64, n0 = (swz >> 6) * 128;  // same-B-panel per XCD
  const int mw = wid >> 1, nw = wid & 1;
  const int K = 1024;

  f32x4 acc[2][4];
  #pragma unroll
  for (int i = 0; i < 2; ++i)
    #pragma unroll
    for (int j = 0; j < 4; ++j) acc[i][j] = (f32x4)0.0f;

  for (int k0 = 0; k0 < K; k0 += 32) {
    {
      int row = tid >> 2, kc = (tid & 3) * 8;               // A: 64 x 32
      async_lds16(aob + (size_t)(m0 + row) * K + k0 + kc, lds_a + tid * 8);
    }
    #pragma unroll
    for (int it = 0; it < 2; ++it) {                        // B: 128 x 32
      int chunk = it * 256 + tid;
      int row = chunk >> 2, kc = (chunk & 3) * 8;
      async_lds16(wT + (size_t)(n0 + row) * K + k0 + kc, lds_b + chunk * 8);
    }
    __syncthreads();
    short8 af[2], bfr[4];
    #pragma unroll
    for (int i = 0; i < 2; ++i)
      af[i] = *(const short8*)&lds_a[(mw * 32 + i * 16 + lr) * 32 + lg * 8];
    #pragma unroll
    for (int j = 0; j < 4; ++j)
      bfr[j] = *(const short8*)&lds_b[(nw * 64 + j * 16 + lr) * 32 + lg * 8];
    #pragma unroll
    for (int i = 0; i < 2; ++i)
      #pragma unroll
      for (int j = 0; j < 4; ++j) acc[i][j] = MFMA16(af[i], bfr[j], acc[i][j]);
    __syncthreads();
  }

  #pragma unroll
  for (int i = 0; i < 2; ++i) {
    int gm = m0 + mw * 32 + i * 16 + lg * 4;
    #pragma unroll
    for (int j = 0; j < 4; ++j) {
      int gc = n0 + nw * 64 + j * 16 + lr;
      float bv = bias[gc];
      #pragma unroll
      for (int r = 0; r < 4; ++r)
        out[(size_t)(gm + r) * 1024 + gc] = acc[i][j][r] + bv;
    }
  }
}

// ---------------- launcher ----------------
extern "C" void kernel_launch(void* const* d_in, const int* in_sizes, int n_in,
                              void* d_out, int out_size, void* d_ws, size_t ws_size,
                              hipStream_t stream) {
  const float* x     = (const float*)d_in[0];  // [2,2048,1024]
  const float* wqkv  = (const float*)d_in[1];  // [1024,3072]
  const float* bqkv  = (const float*)d_in[2];  // [3072]
  const float* wproj = (const float*)d_in[3];  // [1024,1024]
  const float* bproj = (const float*)d_in[4];  // [1024]
  float* out = (float*)d_out;

  char* ws = (char*)d_ws;
  short* xb     = (short*)ws; ws += (size_t)4096 * 1024 * 2;  // 8 MB
  short* wqkvT  = (short*)ws; ws += (size_t)3072 * 1024 * 2;  // 6 MB
  short* wprojT = (short*)ws; ws += (size_t)1024 * 1024 * 2;  // 2 MB
  short* Qb     = (short*)ws; ws += (size_t)32 * 2048 * 64 * 2;  // 8 MB
  short* Kb     = (short*)ws; ws += (size_t)32 * 2048 * 64 * 2;  // 8 MB
  short* Vt     = (short*)ws; ws += (size_t)32 * 64 * 2048 * 2;  // 8 MB
  short* aob    = (short*)ws; ws += (size_t)4096 * 1024 * 2;     // 8 MB
  // total 48 MB workspace

  cast_f32_bf16<<<4096, 256, 0, stream>>>(x, xb, 4096 * 1024 / 4);
  transpose_cast<<<dim3(96, 32), dim3(32, 8), 0, stream>>>(wqkv, wqkvT, 1024, 3072);
  transpose_cast<<<dim3(32, 32), dim3(32, 8), 0, stream>>>(wproj, wprojT, 1024, 1024);
  gemm_qkv<<<768, 256, 0, stream>>>(xb, wqkvT, bqkv, Qb, Kb, Vt);
  attn_fwd<<<512, 512, 0, stream>>>(Qb, Kb, Vt, aob);
  gemm_proj<<<512, 256, 0, stream>>>(aob, wprojT, bproj, out);
}

// Round 6
// 198.910 us; speedup vs baseline: 1.2891x; 1.0782x over previous
//
#include <hip/hip_runtime.h>
#include <hip/hip_bf16.h>
#include <cstdint>
#include <cstddef>

// MHA fused pipeline, bf16 MFMA everywhere, fp32 accumulate.
// B=2 N=2048 E=1024 H=16 D=64; M = B*N = 4096; BH = 32.
// R1: attn LDS XOR-swizzle (verified: SQ_LDS_BANK_CONFLICT=0).
// R2: swapped QK^T -> lane-local softmax (122 -> 76 us, MfmaUtil 11 -> 18).
// R4/R5: attn K/V dbuf prefetch, exp2-domain softmax, defer-max, XCD swizzles,
//        gemm_proj 64x128 (attn 76 -> 67 us).
// R6: GEMMs BK=64 (half the barriers; 32 MFMA/phase) + T2 swizzle on GEMM LDS
//     (BK=64 would be 16-way conflict unswizzled; R3 counters showed 3.1M
//     conflicts already at BK=32), attn setprio around MFMA clusters (T5).

typedef __attribute__((ext_vector_type(8))) short short8;   // 8 bf16 (4 VGPR)
typedef __attribute__((ext_vector_type(4))) short short4v;
typedef __attribute__((ext_vector_type(4))) float f32x4;

#define MFMA16(a, b, c) __builtin_amdgcn_mfma_f32_16x16x32_bf16((a), (b), (c), 0, 0, 0)
#define EXP2F(x) __builtin_amdgcn_exp2f(x)

__device__ __forceinline__ float b2f(short s) {
  union { unsigned u; float f; } x; x.u = ((unsigned)(unsigned short)s) << 16; return x.f;
}
__device__ __forceinline__ short f2b(float f) {  // RNE f32->bf16
  union { float f; unsigned u; } x; x.f = f;
  unsigned r = x.u + 0x7fffu + ((x.u >> 16) & 1u);
  return (short)(r >> 16);
}
__device__ __forceinline__ void async_lds16(const void* g, void* l) {
  __builtin_amdgcn_global_load_lds(
      (const __attribute__((address_space(1))) void*)g,
      (__attribute__((address_space(3))) void*)l, 16, 0, 0);
}

// ---------------- cast x (fp32 -> bf16), vectorized ----------------
__global__ __launch_bounds__(256) void cast_f32_bf16(const float* __restrict__ in,
                                                     short* __restrict__ out, int n4) {
  int idx = blockIdx.x * 256 + threadIdx.x;
  if (idx < n4) {
    f32x4 v = ((const f32x4*)in)[idx];
    short4v o;
    #pragma unroll
    for (int e = 0; e < 4; ++e) o[e] = f2b(v[e]);
    ((short4v*)out)[idx] = o;
  }
}

// ------------- transpose + cast: in [R][C] fp32 -> out [C][R] bf16 -------------
__global__ __launch_bounds__(256) void transpose_cast(const float* __restrict__ in,
                                                      short* __restrict__ out,
                                                      int R, int C) {
  __shared__ float tile[32][33];
  int c0 = blockIdx.x * 32, r0 = blockIdx.y * 32;
  int tx = threadIdx.x, ty = threadIdx.y;  // 32 x 8
  #pragma unroll
  for (int i = ty; i < 32; i += 8)
    tile[i][tx] = in[(size_t)(r0 + i) * C + c0 + tx];
  __syncthreads();
  #pragma unroll
  for (int i = ty; i < 32; i += 8)
    out[(size_t)(c0 + i) * R + r0 + tx] = f2b(tile[tx][i]);
}

// ---------------- GEMM1: qkv = xb @ wqkvT^T + bias, scatter to Q/K/Vt ----------------
// 128x128 tile, BK=64, 1D grid 768, chunked XCD swizzle. LDS [128][64] with
// T2 XOR swizzle: 16B-block idx ^= (row&7); linear LDS dest + pre-swz source.
__global__ __launch_bounds__(256, 3) void gemm_qkv(const short* __restrict__ xb,
                                                   const short* __restrict__ wT,
                                                   const float* __restrict__ bias,
                                                   short* __restrict__ Qb,
                                                   short* __restrict__ Kb,
                                                   short* __restrict__ Vt) {
  __shared__ short lds_a[128 * 64];
  __shared__ short lds_b[128 * 64];
  const int tid = threadIdx.x, wid = tid >> 6, lane = tid & 63;
  const int lg = lane >> 4, lr = lane & 15;
  const int lin = blockIdx.x;
  const int swz = (lin & 7) * 96 + (lin >> 3);   // XCD k owns swz [k*96, (k+1)*96)
  const int m0 = (swz & 31) * 128, n0 = (swz >> 5) * 128;
  const int wr = wid >> 1, wc = wid & 1;
  const int K = 1024;
  const int sm = lr & 7;                         // read-side swizzle mask

  f32x4 acc[4][4];
  #pragma unroll
  for (int i = 0; i < 4; ++i)
    #pragma unroll
    for (int j = 0; j < 4; ++j) acc[i][j] = (f32x4)0.0f;

  for (int k0 = 0; k0 < K; k0 += 64) {
    #pragma unroll
    for (int it = 0; it < 4; ++it) {
      int chunk = it * 256 + tid;
      int row = chunk >> 3, kc = ((chunk & 7) ^ (row & 7)) * 8;  // pre-swz source
      async_lds16(xb + (size_t)(m0 + row) * K + k0 + kc, lds_a + chunk * 8);
      async_lds16(wT + (size_t)(n0 + row) * K + k0 + kc, lds_b + chunk * 8);
    }
    __syncthreads();
    #pragma unroll
    for (int kk = 0; kk < 2; ++kk) {
      short8 af[4], bfr[4];
      #pragma unroll
      for (int i = 0; i < 4; ++i)
        af[i] = *(const short8*)&lds_a[(wr * 64 + i * 16 + lr) * 64 +
                                       (((kk * 4 + lg) ^ sm) * 8)];
      #pragma unroll
      for (int j = 0; j < 4; ++j)
        bfr[j] = *(const short8*)&lds_b[(wc * 64 + j * 16 + lr) * 64 +
                                        (((kk * 4 + lg) ^ sm) * 8)];
      #pragma unroll
      for (int i = 0; i < 4; ++i)
        #pragma unroll
        for (int j = 0; j < 4; ++j) acc[i][j] = MFMA16(af[i], bfr[j], acc[i][j]);
    }
    __syncthreads();
  }

  // epilogue: C/D layout col = lane&15, row = (lane>>4)*4 + reg
  #pragma unroll
  for (int i = 0; i < 4; ++i) {
    int gm = m0 + wr * 64 + i * 16 + lg * 4;  // rows gm..gm+3 (same b: gm%4==0)
    int bb = gm >> 11, n = gm & 2047;
    #pragma unroll
    for (int j = 0; j < 4; ++j) {
      int gc = n0 + wc * 64 + j * 16 + lr;
      float bv = bias[gc];
      int which = gc >> 10;            // uniform per block (n0 % 128 == 0)
      int h = (gc >> 6) & 15;
      int dd = gc & 63;
      size_t qkbase = ((size_t)((bb * 16 + h) * 2048 + n)) * 64 + dd;
      if (which == 2) {                // Vt: r contiguous along n -> pack 8B
        size_t vtbase = ((size_t)((bb * 16 + h) * 64 + dd)) * 2048 + n;
        short4v pv;
        #pragma unroll
        for (int r = 0; r < 4; ++r) pv[r] = f2b(acc[i][j][r] + bv);
        *(short4v*)&Vt[vtbase] = pv;
      } else {
        short* dst = (which == 0) ? Qb : Kb;
        #pragma unroll
        for (int r = 0; r < 4; ++r)
          dst[qkbase + (size_t)r * 64] = f2b(acc[i][j][r] + bv);
      }
    }
  }
}

// ---------------- flash attention (swapped-operand, dbuf, exp2, defer-max) ----------------
// 1D grid 512, 512 threads / 8 waves; wave owns 16 q-rows (q = q0+lr).
// KV tile = 64, double-buffered. Scores in log2 domain; defer-max THR=8.
// R6: s_setprio(1) around MFMA clusters (T5).
__global__ __launch_bounds__(512) void attn_fwd(const short* __restrict__ Qb,
                                                const short* __restrict__ Kb,
                                                const short* __restrict__ Vt,
                                                short* __restrict__ aob) {
  __shared__ short k_lds[2][64 * 64];
  __shared__ short v_lds[2][64 * 64];
  __shared__ short p_lds[8 * 16 * 64];
  const int tid = threadIdx.x, wid = tid >> 6, lane = tid & 63;
  const int lg = lane >> 4, lr = lane & 15;
  const int lin = blockIdx.x;
  const int swz = (lin & 7) * 64 + (lin >> 3);
  const int qt = swz & 15, bh = swz >> 4;   // XCD k owns bh [k*4, k*4+4)
  const int q0 = qt * 128 + wid * 16;
  const short* Qbh = Qb + (size_t)bh * 2048 * 64;
  const short* Kbh = Kb + (size_t)bh * 2048 * 64;
  const short* Vbh = Vt + (size_t)bh * 64 * 2048;
  const int rm = (lr >> 1) & 7;   // read-side swizzle mask (rows indexed by lr)

  // stage one KV tile (linear LDS dest + pre-swizzled global source)
  const int srow = tid >> 3;
  const int ssrc = ((tid & 7) ^ ((srow >> 1) & 7)) * 8;

  // Q fragments hoisted; fold scale 0.125 * log2(e) (exp2-domain scores)
  short8 qf[2];
  #pragma unroll
  for (int kk = 0; kk < 2; ++kk) {
    qf[kk] = *(const short8*)(Qbh + (size_t)(q0 + lr) * 64 + kk * 32 + lg * 8);
    #pragma unroll
    for (int e = 0; e < 8; ++e) qf[kk][e] = f2b(b2f(qf[kk][e]) * 0.1803368801f);
  }

  f32x4 o[4];
  #pragma unroll
  for (int dt = 0; dt < 4; ++dt) o[dt] = (f32x4)0.0f;
  float m_ = -__builtin_inff(), l_ = 0.0f;

  // prologue: stage tile 0 into buf 0
  async_lds16(Kbh + (size_t)srow * 64 + ssrc, &k_lds[0][tid * 8]);
  async_lds16(Vbh + (size_t)srow * 2048 + 0 + ssrc, &v_lds[0][tid * 8]);
  asm volatile("s_waitcnt vmcnt(0)" ::: "memory");
  __syncthreads();

  for (int t = 0; t < 32; ++t) {
    const int cur = t & 1;
    // prefetch next tile into buf^1 (latency hides under this tile's compute)
    if (t + 1 < 32) {
      int kvn = (t + 1) * 64;
      async_lds16(Kbh + (size_t)(kvn + srow) * 64 + ssrc, &k_lds[cur ^ 1][tid * 8]);
      async_lds16(Vbh + (size_t)srow * 2048 + kvn + ssrc, &v_lds[cur ^ 1][tid * 8]);
    }

    // S^T = K Q^T : s[jt][r] = S[q=lr][k=jt*16+lg*4+r], log2 domain
    f32x4 s[4];
    #pragma unroll
    for (int jt = 0; jt < 4; ++jt) s[jt] = (f32x4)0.0f;
    __builtin_amdgcn_s_setprio(1);
    #pragma unroll
    for (int jt = 0; jt < 4; ++jt)
      #pragma unroll
      for (int kk = 0; kk < 2; ++kk) {
        short8 kf = *(const short8*)&k_lds[cur][(jt * 16 + lr) * 64 +
                                               (((kk * 4 + lg) ^ rm) * 8)];
        s[jt] = MFMA16(kf, qf[kk], s[jt]);
      }
    __builtin_amdgcn_s_setprio(0);

    // online softmax, lane-local row + lanes {lr, lr+16, lr+32, lr+48}
    float pmax = s[0][0];
    #pragma unroll
    for (int jt = 0; jt < 4; ++jt)
      #pragma unroll
      for (int r = 0; r < 4; ++r) pmax = fmaxf(pmax, s[jt][r]);
    pmax = fmaxf(pmax, __shfl_xor(pmax, 16));
    pmax = fmaxf(pmax, __shfl_xor(pmax, 32));
    if (!__all(pmax - m_ <= 8.0f)) {      // defer-max: skip rescale if growth small
      float mn = fmaxf(m_, pmax);
      float corr = EXP2F(m_ - mn);        // exp2(-inf) = 0 handles t=0
      m_ = mn;
      l_ *= corr;
      #pragma unroll
      for (int dt = 0; dt < 4; ++dt)
        #pragma unroll
        for (int r = 0; r < 4; ++r) o[dt][r] *= corr;
    }
    float ps = 0.0f;
    #pragma unroll
    for (int jt = 0; jt < 4; ++jt)
      #pragma unroll
      for (int r = 0; r < 4; ++r) {
        float p = EXP2F(s[jt][r] - m_);     // bounded by 2^8 when deferred
        s[jt][r] = p;
        ps += p;
      }
    ps += __shfl_xor(ps, 16);
    ps += __shfl_xor(ps, 32);
    l_ += ps;

    // P -> per-wave LDS [16 q][64 k], swizzled, packed b64 writes
    #pragma unroll
    for (int jt = 0; jt < 4; ++jt) {
      short4v pv;
      #pragma unroll
      for (int r = 0; r < 4; ++r) pv[r] = f2b(s[jt][r]);
      *(short4v*)&p_lds[wid * 1024 + lr * 64 +
                        (((jt * 2 + (lg >> 1)) ^ rm) * 8) + (lg & 1) * 4] = pv;
    }
    asm volatile("s_waitcnt lgkmcnt(0)" ::: "memory");
    __builtin_amdgcn_sched_barrier(0);

    // O^T += V^T P^T : o[dt] covers d = dt*16+lg*4+r for q = lr
    __builtin_amdgcn_s_setprio(1);
    #pragma unroll
    for (int kk = 0; kk < 2; ++kk) {
      short8 pa = *(const short8*)&p_lds[wid * 1024 + lr * 64 +
                                         (((kk * 4 + lg) ^ rm) * 8)];
      #pragma unroll
      for (int dt = 0; dt < 4; ++dt) {
        short8 vb = *(const short8*)&v_lds[cur][(dt * 16 + lr) * 64 +
                                               (((kk * 4 + lg) ^ rm) * 8)];
        o[dt] = MFMA16(vb, pa, o[dt]);
      }
    }
    __builtin_amdgcn_s_setprio(0);
    // single drain+barrier per tile (prefetch was issued ~2000 cyc ago)
    asm volatile("s_waitcnt vmcnt(0)" ::: "memory");
    __syncthreads();
  }

  // epilogue: out layout [b][n][h*64+d] bf16; n = q0+lr, packed 8B stores
  const int bb = bh >> 4, h = bh & 15;
  const float inv_l = __frcp_rn(l_);
  #pragma unroll
  for (int dt = 0; dt < 4; ++dt) {
    short4v ov;
    #pragma unroll
    for (int r = 0; r < 4; ++r) ov[r] = f2b(o[dt][r] * inv_l);
    *(short4v*)&aob[(size_t)(bb * 2048 + q0 + lr) * 1024 + h * 64 + dt * 16 + lg * 4] = ov;
  }
}

// ---------------- GEMM2: out = aob @ wprojT^T + b_proj (fp32 out) ----------------
// 64x128 tile, BK=64, 1D grid 512 (2 blocks/CU), XCD swizzle, T2 LDS swizzle.
__global__ __launch_bounds__(256, 2) void gemm_proj(const short* __restrict__ aob,
                                                    const short* __restrict__ wT,
                                                    const float* __restrict__ bias,
                                                    float* __restrict__ out) {
  __shared__ short lds_a[64 * 64];
  __shared__ short lds_b[128 * 64];
  const int tid = threadIdx.x, wid = tid >> 6, lane = tid & 63;
  const int lg = lane >> 4, lr = lane & 15;
  const int lin = blockIdx.x;
  const int swz = (lin & 7) * 64 + (lin >> 3);
  const int m0 = (swz & 63) * 64, n0 = (swz >> 6) * 128;  // same-B-panel per XCD
  const int mw = wid >> 1, nw = wid & 1;
  const int K = 1024;
  const int sm = lr & 7;

  f32x4 acc[2][4];
  #pragma unroll
  for (int i = 0; i < 2; ++i)
    #pragma unroll
    for (int j = 0; j < 4; ++j) acc[i][j] = (f32x4)0.0f;

  for (int k0 = 0; k0 < K; k0 += 64) {
    #pragma unroll
    for (int it = 0; it < 2; ++it) {                        // A: 64 x 64
      int chunk = it * 256 + tid;
      int row = chunk >> 3, kc = ((chunk & 7) ^ (row & 7)) * 8;
      async_lds16(aob + (size_t)(m0 + row) * K + k0 + kc, lds_a + chunk * 8);
    }
    #pragma unroll
    for (int it = 0; it < 4; ++it) {                        // B: 128 x 64
      int chunk = it * 256 + tid;
      int row = chunk >> 3, kc = ((chunk & 7) ^ (row & 7)) * 8;
      async_lds16(wT + (size_t)(n0 + row) * K + k0 + kc, lds_b + chunk * 8);
    }
    __syncthreads();
    #pragma unroll
    for (int kk = 0; kk < 2; ++kk) {
      short8 af[2], bfr[4];
      #pragma unroll
      for (int i = 0; i < 2; ++i)
        af[i] = *(const short8*)&lds_a[(mw * 32 + i * 16 + lr) * 64 +
                                       (((kk * 4 + lg) ^ sm) * 8)];
      #pragma unroll
      for (int j = 0; j < 4; ++j)
        bfr[j] = *(const short8*)&lds_b[(nw * 64 + j * 16 + lr) * 64 +
                                        (((kk * 4 + lg) ^ sm) * 8)];
      #pragma unroll
      for (int i = 0; i < 2; ++i)
        #pragma unroll
        for (int j = 0; j < 4; ++j) acc[i][j] = MFMA16(af[i], bfr[j], acc[i][j]);
    }
    __syncthreads();
  }

  #pragma unroll
  for (int i = 0; i < 2; ++i) {
    int gm = m0 + mw * 32 + i * 16 + lg * 4;
    #pragma unroll
    for (int j = 0; j < 4; ++j) {
      int gc = n0 + nw * 64 + j * 16 + lr;
      float bv = bias[gc];
      #pragma unroll
      for (int r = 0; r < 4; ++r)
        out[(size_t)(gm + r) * 1024 + gc] = acc[i][j][r] + bv;
    }
  }
}

// ---------------- launcher ----------------
extern "C" void kernel_launch(void* const* d_in, const int* in_sizes, int n_in,
                              void* d_out, int out_size, void* d_ws, size_t ws_size,
                              hipStream_t stream) {
  const float* x     = (const float*)d_in[0];  // [2,2048,1024]
  const float* wqkv  = (const float*)d_in[1];  // [1024,3072]
  const float* bqkv  = (const float*)d_in[2];  // [3072]
  const float* wproj = (const float*)d_in[3];  // [1024,1024]
  const float* bproj = (const float*)d_in[4];  // [1024]
  float* out = (float*)d_out;

  char* ws = (char*)d_ws;
  short* xb     = (short*)ws; ws += (size_t)4096 * 1024 * 2;  // 8 MB
  short* wqkvT  = (short*)ws; ws += (size_t)3072 * 1024 * 2;  // 6 MB
  short* wprojT = (short*)ws; ws += (size_t)1024 * 1024 * 2;  // 2 MB
  short* Qb     = (short*)ws; ws += (size_t)32 * 2048 * 64 * 2;  // 8 MB
  short* Kb     = (short*)ws; ws += (size_t)32 * 2048 * 64 * 2;  // 8 MB
  short* Vt     = (short*)ws; ws += (size_t)32 * 64 * 2048 * 2;  // 8 MB
  short* aob    = (short*)ws; ws += (size_t)4096 * 1024 * 2;     // 8 MB
  // total 48 MB workspace

  cast_f32_bf16<<<4096, 256, 0, stream>>>(x, xb, 4096 * 1024 / 4);
  transpose_cast<<<dim3(96, 32), dim3(32, 8), 0, stream>>>(wqkv, wqkvT, 1024, 3072);
  transpose_cast<<<dim3(32, 32), dim3(32, 8), 0, stream>>>(wproj, wprojT, 1024, 1024);
  gemm_qkv<<<768, 256, 0, stream>>>(xb, wqkvT, bqkv, Qb, Kb, Vt);
  attn_fwd<<<512, 512, 0, stream>>>(Qb, Kb, Vt, aob);
  gemm_proj<<<512, 256, 0, stream>>>(aob, wprojT, bproj, out);
}

// Round 8
// 193.906 us; speedup vs baseline: 1.3224x; 1.0258x over previous
//
#include <hip/hip_runtime.h>
#include <hip/hip_bf16.h>
#include <cstdint>
#include <cstddef>

// MHA fused pipeline, bf16 MFMA everywhere, fp32 accumulate.
// B=2 N=2048 E=1024 H=16 D=64; M = B*N = 4096; BH = 32.
// R1: attn LDS XOR-swizzle (verified: SQ_LDS_BANK_CONFLICT=0).
// R2: swapped QK^T -> lane-local softmax (122 -> 76 us, MfmaUtil 11 -> 18).
// R4/R5: attn K/V dbuf prefetch, exp2 softmax, defer-max, XCD swizzles (-> 67 us).
// R6: GEMMs BK=64 + T2 swizzle (total -16 us); attn setprio REGRESSED (67->70.6).
// R7: revert setprio (m190 lockstep-null pattern); native bf16 casts
//     (compiler cvt_pk fusion, m240); tree-reduce pmax/ps (dep depth 16->4);
//     fuse exp->pack->ds_write per jt.
// R8: resubmit of R7 (infra failure, kernel never ran).

typedef __attribute__((ext_vector_type(8))) short short8;   // 8 bf16 (4 VGPR)
typedef __attribute__((ext_vector_type(4))) short short4v;
typedef __attribute__((ext_vector_type(4))) float f32x4;

#define MFMA16(a, b, c) __builtin_amdgcn_mfma_f32_16x16x32_bf16((a), (b), (c), 0, 0, 0)
#define EXP2F(x) __builtin_amdgcn_exp2f(x)

__device__ __forceinline__ float b2f(short s) {
  union { unsigned u; float f; } x; x.u = ((unsigned)(unsigned short)s) << 16; return x.f;
}
__device__ __forceinline__ short f2b(float f) {  // native RNE cast (cvt_pk-fusable)
  union { __hip_bfloat16 h; short s; } u; u.h = __float2bfloat16(f); return u.s;
}
__device__ __forceinline__ void async_lds16(const void* g, void* l) {
  __builtin_amdgcn_global_load_lds(
      (const __attribute__((address_space(1))) void*)g,
      (__attribute__((address_space(3))) void*)l, 16, 0, 0);
}

// ---------------- cast x (fp32 -> bf16), vectorized ----------------
__global__ __launch_bounds__(256) void cast_f32_bf16(const float* __restrict__ in,
                                                     short* __restrict__ out, int n4) {
  int idx = blockIdx.x * 256 + threadIdx.x;
  if (idx < n4) {
    f32x4 v = ((const f32x4*)in)[idx];
    short4v o;
    #pragma unroll
    for (int e = 0; e < 4; ++e) o[e] = f2b(v[e]);
    ((short4v*)out)[idx] = o;
  }
}

// ------------- transpose + cast: in [R][C] fp32 -> out [C][R] bf16 -------------
__global__ __launch_bounds__(256) void transpose_cast(const float* __restrict__ in,
                                                      short* __restrict__ out,
                                                      int R, int C) {
  __shared__ float tile[32][33];
  int c0 = blockIdx.x * 32, r0 = blockIdx.y * 32;
  int tx = threadIdx.x, ty = threadIdx.y;  // 32 x 8
  #pragma unroll
  for (int i = ty; i < 32; i += 8)
    tile[i][tx] = in[(size_t)(r0 + i) * C + c0 + tx];
  __syncthreads();
  #pragma unroll
  for (int i = ty; i < 32; i += 8)
    out[(size_t)(c0 + i) * R + r0 + tx] = f2b(tile[tx][i]);
}

// ---------------- GEMM1: qkv = xb @ wqkvT^T + bias, scatter to Q/K/Vt ----------------
// 128x128 tile, BK=64, 1D grid 768, chunked XCD swizzle. LDS [128][64] with
// T2 XOR swizzle: 16B-block idx ^= (row&7); linear LDS dest + pre-swz source.
__global__ __launch_bounds__(256, 3) void gemm_qkv(const short* __restrict__ xb,
                                                   const short* __restrict__ wT,
                                                   const float* __restrict__ bias,
                                                   short* __restrict__ Qb,
                                                   short* __restrict__ Kb,
                                                   short* __restrict__ Vt) {
  __shared__ short lds_a[128 * 64];
  __shared__ short lds_b[128 * 64];
  const int tid = threadIdx.x, wid = tid >> 6, lane = tid & 63;
  const int lg = lane >> 4, lr = lane & 15;
  const int lin = blockIdx.x;
  const int swz = (lin & 7) * 96 + (lin >> 3);   // XCD k owns swz [k*96, (k+1)*96)
  const int m0 = (swz & 31) * 128, n0 = (swz >> 5) * 128;
  const int wr = wid >> 1, wc = wid & 1;
  const int K = 1024;
  const int sm = lr & 7;                         // read-side swizzle mask

  f32x4 acc[4][4];
  #pragma unroll
  for (int i = 0; i < 4; ++i)
    #pragma unroll
    for (int j = 0; j < 4; ++j) acc[i][j] = (f32x4)0.0f;

  for (int k0 = 0; k0 < K; k0 += 64) {
    #pragma unroll
    for (int it = 0; it < 4; ++it) {
      int chunk = it * 256 + tid;
      int row = chunk >> 3, kc = ((chunk & 7) ^ (row & 7)) * 8;  // pre-swz source
      async_lds16(xb + (size_t)(m0 + row) * K + k0 + kc, lds_a + chunk * 8);
      async_lds16(wT + (size_t)(n0 + row) * K + k0 + kc, lds_b + chunk * 8);
    }
    __syncthreads();
    #pragma unroll
    for (int kk = 0; kk < 2; ++kk) {
      short8 af[4], bfr[4];
      #pragma unroll
      for (int i = 0; i < 4; ++i)
        af[i] = *(const short8*)&lds_a[(wr * 64 + i * 16 + lr) * 64 +
                                       (((kk * 4 + lg) ^ sm) * 8)];
      #pragma unroll
      for (int j = 0; j < 4; ++j)
        bfr[j] = *(const short8*)&lds_b[(wc * 64 + j * 16 + lr) * 64 +
                                        (((kk * 4 + lg) ^ sm) * 8)];
      #pragma unroll
      for (int i = 0; i < 4; ++i)
        #pragma unroll
        for (int j = 0; j < 4; ++j) acc[i][j] = MFMA16(af[i], bfr[j], acc[i][j]);
    }
    __syncthreads();
  }

  // epilogue: C/D layout col = lane&15, row = (lane>>4)*4 + reg
  #pragma unroll
  for (int i = 0; i < 4; ++i) {
    int gm = m0 + wr * 64 + i * 16 + lg * 4;  // rows gm..gm+3 (same b: gm%4==0)
    int bb = gm >> 11, n = gm & 2047;
    #pragma unroll
    for (int j = 0; j < 4; ++j) {
      int gc = n0 + wc * 64 + j * 16 + lr;
      float bv = bias[gc];
      int which = gc >> 10;            // uniform per block (n0 % 128 == 0)
      int h = (gc >> 6) & 15;
      int dd = gc & 63;
      size_t qkbase = ((size_t)((bb * 16 + h) * 2048 + n)) * 64 + dd;
      if (which == 2) {                // Vt: r contiguous along n -> pack 8B
        size_t vtbase = ((size_t)((bb * 16 + h) * 64 + dd)) * 2048 + n;
        short4v pv;
        #pragma unroll
        for (int r = 0; r < 4; ++r) pv[r] = f2b(acc[i][j][r] + bv);
        *(short4v*)&Vt[vtbase] = pv;
      } else {
        short* dst = (which == 0) ? Qb : Kb;
        #pragma unroll
        for (int r = 0; r < 4; ++r)
          dst[qkbase + (size_t)r * 64] = f2b(acc[i][j][r] + bv);
      }
    }
  }
}

// ---------------- flash attention (swapped-operand, dbuf, exp2, defer-max) ----------------
// 1D grid 512, 512 threads / 8 waves; wave owns 16 q-rows (q = q0+lr).
// KV tile = 64, double-buffered. Scores in log2 domain; defer-max THR=8.
// R7: no setprio; tree-reduced pmax/ps; fused exp->pack->ds_write per jt.
__global__ __launch_bounds__(512) void attn_fwd(const short* __restrict__ Qb,
                                                const short* __restrict__ Kb,
                                                const short* __restrict__ Vt,
                                                short* __restrict__ aob) {
  __shared__ short k_lds[2][64 * 64];
  __shared__ short v_lds[2][64 * 64];
  __shared__ short p_lds[8 * 16 * 64];
  const int tid = threadIdx.x, wid = tid >> 6, lane = tid & 63;
  const int lg = lane >> 4, lr = lane & 15;
  const int lin = blockIdx.x;
  const int swz = (lin & 7) * 64 + (lin >> 3);
  const int qt = swz & 15, bh = swz >> 4;   // XCD k owns bh [k*4, k*4+4)
  const int q0 = qt * 128 + wid * 16;
  const short* Qbh = Qb + (size_t)bh * 2048 * 64;
  const short* Kbh = Kb + (size_t)bh * 2048 * 64;
  const short* Vbh = Vt + (size_t)bh * 64 * 2048;
  const int rm = (lr >> 1) & 7;   // read-side swizzle mask (rows indexed by lr)

  // stage one KV tile (linear LDS dest + pre-swizzled global source)
  const int srow = tid >> 3;
  const int ssrc = ((tid & 7) ^ ((srow >> 1) & 7)) * 8;

  // loop-invariant p_lds write/read offsets
  int pw[4], pr[2];
  #pragma unroll
  for (int jt = 0; jt < 4; ++jt)
    pw[jt] = wid * 1024 + lr * 64 + (((jt * 2 + (lg >> 1)) ^ rm) * 8) + (lg & 1) * 4;
  #pragma unroll
  for (int kk = 0; kk < 2; ++kk)
    pr[kk] = wid * 1024 + lr * 64 + (((kk * 4 + lg) ^ rm) * 8);

  // Q fragments hoisted; fold scale 0.125 * log2(e) (exp2-domain scores)
  short8 qf[2];
  #pragma unroll
  for (int kk = 0; kk < 2; ++kk) {
    qf[kk] = *(const short8*)(Qbh + (size_t)(q0 + lr) * 64 + kk * 32 + lg * 8);
    #pragma unroll
    for (int e = 0; e < 8; ++e) qf[kk][e] = f2b(b2f(qf[kk][e]) * 0.1803368801f);
  }

  f32x4 o[4];
  #pragma unroll
  for (int dt = 0; dt < 4; ++dt) o[dt] = (f32x4)0.0f;
  float m_ = -__builtin_inff(), l_ = 0.0f;

  // prologue: stage tile 0 into buf 0
  async_lds16(Kbh + (size_t)srow * 64 + ssrc, &k_lds[0][tid * 8]);
  async_lds16(Vbh + (size_t)srow * 2048 + 0 + ssrc, &v_lds[0][tid * 8]);
  asm volatile("s_waitcnt vmcnt(0)" ::: "memory");
  __syncthreads();

  for (int t = 0; t < 32; ++t) {
    const int cur = t & 1;
    // prefetch next tile into buf^1 (latency hides under this tile's compute)
    if (t + 1 < 32) {
      int kvn = (t + 1) * 64;
      async_lds16(Kbh + (size_t)(kvn + srow) * 64 + ssrc, &k_lds[cur ^ 1][tid * 8]);
      async_lds16(Vbh + (size_t)srow * 2048 + kvn + ssrc, &v_lds[cur ^ 1][tid * 8]);
    }

    // S^T = K Q^T : s[jt][r] = S[q=lr][k=jt*16+lg*4+r], log2 domain
    f32x4 s[4];
    #pragma unroll
    for (int jt = 0; jt < 4; ++jt) s[jt] = (f32x4)0.0f;
    #pragma unroll
    for (int jt = 0; jt < 4; ++jt)
      #pragma unroll
      for (int kk = 0; kk < 2; ++kk) {
        short8 kf = *(const short8*)&k_lds[cur][(jt * 16 + lr) * 64 +
                                               (((kk * 4 + lg) ^ rm) * 8)];
        s[jt] = MFMA16(kf, qf[kk], s[jt]);
      }

    // pmax: depth-4 tree (max3-fusable)
    float mj[4];
    #pragma unroll
    for (int jt = 0; jt < 4; ++jt)
      mj[jt] = fmaxf(fmaxf(s[jt][0], s[jt][1]), fmaxf(s[jt][2], s[jt][3]));
    float pmax = fmaxf(fmaxf(mj[0], mj[1]), fmaxf(mj[2], mj[3]));
    pmax = fmaxf(pmax, __shfl_xor(pmax, 16));
    pmax = fmaxf(pmax, __shfl_xor(pmax, 32));
    if (!__all(pmax - m_ <= 8.0f)) {      // defer-max: skip rescale if growth small
      float mn = fmaxf(m_, pmax);
      float corr = EXP2F(m_ - mn);        // exp2(-inf) = 0 handles t=0
      m_ = mn;
      l_ *= corr;
      #pragma unroll
      for (int dt = 0; dt < 4; ++dt)
        #pragma unroll
        for (int r = 0; r < 4; ++r) o[dt][r] *= corr;
    }

    // fused exp -> pack -> P ds_write per jt; depth-4 sum tree
    float psj[4];
    #pragma unroll
    for (int jt = 0; jt < 4; ++jt) {
      float p0 = EXP2F(s[jt][0] - m_), p1 = EXP2F(s[jt][1] - m_);
      float p2 = EXP2F(s[jt][2] - m_), p3 = EXP2F(s[jt][3] - m_);
      short4v pv;
      pv[0] = f2b(p0); pv[1] = f2b(p1); pv[2] = f2b(p2); pv[3] = f2b(p3);
      *(short4v*)&p_lds[pw[jt]] = pv;
      psj[jt] = (p0 + p1) + (p2 + p3);
    }
    float ps = (psj[0] + psj[1]) + (psj[2] + psj[3]);
    ps += __shfl_xor(ps, 16);
    ps += __shfl_xor(ps, 32);
    l_ += ps;

    asm volatile("s_waitcnt lgkmcnt(0)" ::: "memory");
    __builtin_amdgcn_sched_barrier(0);

    // O^T += V^T P^T : o[dt] covers d = dt*16+lg*4+r for q = lr
    #pragma unroll
    for (int kk = 0; kk < 2; ++kk) {
      short8 pa = *(const short8*)&p_lds[pr[kk]];
      #pragma unroll
      for (int dt = 0; dt < 4; ++dt) {
        short8 vb = *(const short8*)&v_lds[cur][(dt * 16 + lr) * 64 +
                                               (((kk * 4 + lg) ^ rm) * 8)];
        o[dt] = MFMA16(vb, pa, o[dt]);
      }
    }
    // single drain+barrier per tile (prefetch was issued ~2000 cyc ago)
    asm volatile("s_waitcnt vmcnt(0)" ::: "memory");
    __syncthreads();
  }

  // epilogue: out layout [b][n][h*64+d] bf16; n = q0+lr, packed 8B stores
  const int bb = bh >> 4, h = bh & 15;
  const float inv_l = __frcp_rn(l_);
  #pragma unroll
  for (int dt = 0; dt < 4; ++dt) {
    short4v ov;
    #pragma unroll
    for (int r = 0; r < 4; ++r) ov[r] = f2b(o[dt][r] * inv_l);
    *(short4v*)&aob[(size_t)(bb * 2048 + q0 + lr) * 1024 + h * 64 + dt * 16 + lg * 4] = ov;
  }
}

// ---------------- GEMM2: out = aob @ wprojT^T + b_proj (fp32 out) ----------------
// 64x128 tile, BK=64, 1D grid 512 (2 blocks/CU), XCD swizzle, T2 LDS swizzle.
__global__ __launch_bounds__(256, 2) void gemm_proj(const short* __restrict__ aob,
                                                    const short* __restrict__ wT,
                                                    const float* __restrict__ bias,
                                                    float* __restrict__ out) {
  __shared__ short lds_a[64 * 64];
  __shared__ short lds_b[128 * 64];
  const int tid = threadIdx.x, wid = tid >> 6, lane = tid & 63;
  const int lg = lane >> 4, lr = lane & 15;
  const int lin = blockIdx.x;
  const int swz = (lin & 7) * 64 + (lin >> 3);
  const int m0 = (swz & 63) * 64, n0 = (swz >> 6) * 128;  // same-B-panel per XCD
  const int mw = wid >> 1, nw = wid & 1;
  const int K = 1024;
  const int sm = lr & 7;

  f32x4 acc[2][4];
  #pragma unroll
  for (int i = 0; i < 2; ++i)
    #pragma unroll
    for (int j = 0; j < 4; ++j) acc[i][j] = (f32x4)0.0f;

  for (int k0 = 0; k0 < K; k0 += 64) {
    #pragma unroll
    for (int it = 0; it < 2; ++it) {                        // A: 64 x 64
      int chunk = it * 256 + tid;
      int row = chunk >> 3, kc = ((chunk & 7) ^ (row & 7)) * 8;
      async_lds16(aob + (size_t)(m0 + row) * K + k0 + kc, lds_a + chunk * 8);
    }
    #pragma unroll
    for (int it = 0; it < 4; ++it) {                        // B: 128 x 64
      int chunk = it * 256 + tid;
      int row = chunk >> 3, kc = ((chunk & 7) ^ (row & 7)) * 8;
      async_lds16(wT + (size_t)(n0 + row) * K + k0 + kc, lds_b + chunk * 8);
    }
    __syncthreads();
    #pragma unroll
    for (int kk = 0; kk < 2; ++kk) {
      short8 af[2], bfr[4];
      #pragma unroll
      for (int i = 0; i < 2; ++i)
        af[i] = *(const short8*)&lds_a[(mw * 32 + i * 16 + lr) * 64 +
                                       (((kk * 4 + lg) ^ sm) * 8)];
      #pragma unroll
      for (int j = 0; j < 4; ++j)
        bfr[j] = *(const short8*)&lds_b[(nw * 64 + j * 16 + lr) * 64 +
                                        (((kk * 4 + lg) ^ sm) * 8)];
      #pragma unroll
      for (int i = 0; i < 2; ++i)
        #pragma unroll
        for (int j = 0; j < 4; ++j) acc[i][j] = MFMA16(af[i], bfr[j], acc[i][j]);
    }
    __syncthreads();
  }

  #pragma unroll
  for (int i = 0; i < 2; ++i) {
    int gm = m0 + mw * 32 + i * 16 + lg * 4;
    #pragma unroll
    for (int j = 0; j < 4; ++j) {
      int gc = n0 + nw * 64 + j * 16 + lr;
      float bv = bias[gc];
      #pragma unroll
      for (int r = 0; r < 4; ++r)
        out[(size_t)(gm + r) * 1024 + gc] = acc[i][j][r] + bv;
    }
  }
}

// ---------------- launcher ----------------
extern "C" void kernel_launch(void* const* d_in, const int* in_sizes, int n_in,
                              void* d_out, int out_size, void* d_ws, size_t ws_size,
                              hipStream_t stream) {
  const float* x     = (const float*)d_in[0];  // [2,2048,1024]
  const float* wqkv  = (const float*)d_in[1];  // [1024,3072]
  const float* bqkv  = (const float*)d_in[2];  // [3072]
  const float* wproj = (const float*)d_in[3];  // [1024,1024]
  const float* bproj = (const float*)d_in[4];  // [1024]
  float* out = (float*)d_out;

  char* ws = (char*)d_ws;
  short* xb     = (short*)ws; ws += (size_t)4096 * 1024 * 2;  // 8 MB
  short* wqkvT  = (short*)ws; ws += (size_t)3072 * 1024 * 2;  // 6 MB
  short* wprojT = (short*)ws; ws += (size_t)1024 * 1024 * 2;  // 2 MB
  short* Qb     = (short*)ws; ws += (size_t)32 * 2048 * 64 * 2;  // 8 MB
  short* Kb     = (short*)ws; ws += (size_t)32 * 2048 * 64 * 2;  // 8 MB
  short* Vt     = (short*)ws; ws += (size_t)32 * 64 * 2048 * 2;  // 8 MB
  short* aob    = (short*)ws; ws += (size_t)4096 * 1024 * 2;     // 8 MB
  // total 48 MB workspace

  cast_f32_bf16<<<4096, 256, 0, stream>>>(x, xb, 4096 * 1024 / 4);
  transpose_cast<<<dim3(96, 32), dim3(32, 8), 0, stream>>>(wqkv, wqkvT, 1024, 3072);
  transpose_cast<<<dim3(32, 32), dim3(32, 8), 0, stream>>>(wproj, wprojT, 1024, 1024);
  gemm_qkv<<<768, 256, 0, stream>>>(xb, wqkvT, bqkv, Qb, Kb, Vt);
  attn_fwd<<<512, 512, 0, stream>>>(Qb, Kb, Vt, aob);
  gemm_proj<<<512, 256, 0, stream>>>(aob, wprojT, bproj, out);
}

// Round 10
// 191.978 us; speedup vs baseline: 1.3356x; 1.0100x over previous
//
#include <hip/hip_runtime.h>
#include <hip/hip_bf16.h>
#include <cstdint>
#include <cstddef>

// MHA fused pipeline, bf16 MFMA everywhere, fp32 accumulate.
// B=2 N=2048 E=1024 H=16 D=64; M = B*N = 4096; BH = 32.
// R1: attn LDS XOR-swizzle (verified: SQ_LDS_BANK_CONFLICT=0).
// R2: swapped QK^T -> lane-local softmax (122 -> 76 us).
// R4/R5: K/V dbuf prefetch, exp2 softmax, defer-max, XCD swizzles (-> 67 us).
// R6: GEMMs BK=64 + T2 swizzle; attn setprio REGRESSED (-> 70.6).
// R7/R8: revert setprio, native cvt_pk casts, tree reductions (-> 63.3 us).
// R9: l-sum via ones-MFMA (kills 15 adds + 2 bpermutes/tile, rides idle MFMA
//     pipe); drop explicit lgkm-drain+sched_barrier (compiler counts the
//     minimal lgkmcnt itself); cast grid-stride 1024 blocks; 64x64 transposes.
// R10: resubmit of R9 (GPU acquisition timeout, kernel never ran).

typedef __attribute__((ext_vector_type(8))) short short8;   // 8 bf16 (4 VGPR)
typedef __attribute__((ext_vector_type(4))) short short4v;
typedef __attribute__((ext_vector_type(4))) float f32x4;

#define MFMA16(a, b, c) __builtin_amdgcn_mfma_f32_16x16x32_bf16((a), (b), (c), 0, 0, 0)
#define EXP2F(x) __builtin_amdgcn_exp2f(x)

__device__ __forceinline__ float b2f(short s) {
  union { unsigned u; float f; } x; x.u = ((unsigned)(unsigned short)s) << 16; return x.f;
}
__device__ __forceinline__ short f2b(float f) {  // native RNE cast (cvt_pk-fusable)
  union { __hip_bfloat16 h; short s; } u; u.h = __float2bfloat16(f); return u.s;
}
__device__ __forceinline__ void async_lds16(const void* g, void* l) {
  __builtin_amdgcn_global_load_lds(
      (const __attribute__((address_space(1))) void*)g,
      (__attribute__((address_space(3))) void*)l, 16, 0, 0);
}

// ---------------- cast x (fp32 -> bf16), vectorized, grid-stride ----------------
__global__ __launch_bounds__(256) void cast_f32_bf16(const float* __restrict__ in,
                                                     short* __restrict__ out, int n4) {
  for (int idx = blockIdx.x * 256 + threadIdx.x; idx < n4; idx += 1024 * 256) {
    f32x4 v = ((const f32x4*)in)[idx];
    short4v o;
    #pragma unroll
    for (int e = 0; e < 4; ++e) o[e] = f2b(v[e]);
    ((short4v*)out)[idx] = o;
  }
}

// ------------- transpose + cast: in [R][C] fp32 -> out [C][R] bf16 (64x64) -------------
__global__ __launch_bounds__(256) void transpose_cast(const float* __restrict__ in,
                                                      short* __restrict__ out,
                                                      int R, int C) {
  __shared__ float tile[64][65];
  int c0 = blockIdx.x * 64, r0 = blockIdx.y * 64;
  int tx = threadIdx.x & 63, ty = threadIdx.x >> 6;  // 64 x 4
  #pragma unroll
  for (int i = ty; i < 64; i += 4)
    tile[i][tx] = in[(size_t)(r0 + i) * C + c0 + tx];
  __syncthreads();
  #pragma unroll
  for (int i = ty; i < 64; i += 4)
    out[(size_t)(c0 + i) * R + r0 + tx] = f2b(tile[tx][i]);
}

// ---------------- GEMM1: qkv = xb @ wqkvT^T + bias, scatter to Q/K/Vt ----------------
// 128x128 tile, BK=64, 1D grid 768, chunked XCD swizzle. LDS [128][64] with
// T2 XOR swizzle: 16B-block idx ^= (row&7); linear LDS dest + pre-swz source.
__global__ __launch_bounds__(256, 3) void gemm_qkv(const short* __restrict__ xb,
                                                   const short* __restrict__ wT,
                                                   const float* __restrict__ bias,
                                                   short* __restrict__ Qb,
                                                   short* __restrict__ Kb,
                                                   short* __restrict__ Vt) {
  __shared__ short lds_a[128 * 64];
  __shared__ short lds_b[128 * 64];
  const int tid = threadIdx.x, wid = tid >> 6, lane = tid & 63;
  const int lg = lane >> 4, lr = lane & 15;
  const int lin = blockIdx.x;
  const int swz = (lin & 7) * 96 + (lin >> 3);   // XCD k owns swz [k*96, (k+1)*96)
  const int m0 = (swz & 31) * 128, n0 = (swz >> 5) * 128;
  const int wr = wid >> 1, wc = wid & 1;
  const int K = 1024;
  const int sm = lr & 7;                         // read-side swizzle mask

  f32x4 acc[4][4];
  #pragma unroll
  for (int i = 0; i < 4; ++i)
    #pragma unroll
    for (int j = 0; j < 4; ++j) acc[i][j] = (f32x4)0.0f;

  for (int k0 = 0; k0 < K; k0 += 64) {
    #pragma unroll
    for (int it = 0; it < 4; ++it) {
      int chunk = it * 256 + tid;
      int row = chunk >> 3, kc = ((chunk & 7) ^ (row & 7)) * 8;  // pre-swz source
      async_lds16(xb + (size_t)(m0 + row) * K + k0 + kc, lds_a + chunk * 8);
      async_lds16(wT + (size_t)(n0 + row) * K + k0 + kc, lds_b + chunk * 8);
    }
    __syncthreads();
    #pragma unroll
    for (int kk = 0; kk < 2; ++kk) {
      short8 af[4], bfr[4];
      #pragma unroll
      for (int i = 0; i < 4; ++i)
        af[i] = *(const short8*)&lds_a[(wr * 64 + i * 16 + lr) * 64 +
                                       (((kk * 4 + lg) ^ sm) * 8)];
      #pragma unroll
      for (int j = 0; j < 4; ++j)
        bfr[j] = *(const short8*)&lds_b[(wc * 64 + j * 16 + lr) * 64 +
                                        (((kk * 4 + lg) ^ sm) * 8)];
      #pragma unroll
      for (int i = 0; i < 4; ++i)
        #pragma unroll
        for (int j = 0; j < 4; ++j) acc[i][j] = MFMA16(af[i], bfr[j], acc[i][j]);
    }
    __syncthreads();
  }

  // epilogue: C/D layout col = lane&15, row = (lane>>4)*4 + reg
  #pragma unroll
  for (int i = 0; i < 4; ++i) {
    int gm = m0 + wr * 64 + i * 16 + lg * 4;  // rows gm..gm+3 (same b: gm%4==0)
    int bb = gm >> 11, n = gm & 2047;
    #pragma unroll
    for (int j = 0; j < 4; ++j) {
      int gc = n0 + wc * 64 + j * 16 + lr;
      float bv = bias[gc];
      int which = gc >> 10;            // uniform per block (n0 % 128 == 0)
      int h = (gc >> 6) & 15;
      int dd = gc & 63;
      size_t qkbase = ((size_t)((bb * 16 + h) * 2048 + n)) * 64 + dd;
      if (which == 2) {                // Vt: r contiguous along n -> pack 8B
        size_t vtbase = ((size_t)((bb * 16 + h) * 64 + dd)) * 2048 + n;
        short4v pv;
        #pragma unroll
        for (int r = 0; r < 4; ++r) pv[r] = f2b(acc[i][j][r] + bv);
        *(short4v*)&Vt[vtbase] = pv;
      } else {
        short* dst = (which == 0) ? Qb : Kb;
        #pragma unroll
        for (int r = 0; r < 4; ++r)
          dst[qkbase + (size_t)r * 64] = f2b(acc[i][j][r] + bv);
      }
    }
  }
}

// ---------------- flash attention (swapped-operand, dbuf, exp2, defer-max) ----------------
// 1D grid 512, 512 threads / 8 waves; wave owns 16 q-rows (q = q0+lr).
// KV tile = 64, double-buffered. Scores in log2 domain; defer-max THR=8.
// R9: denominator l accumulated via ones-MFMA (o_l); no explicit lgkm drain.
__global__ __launch_bounds__(512) void attn_fwd(const short* __restrict__ Qb,
                                                const short* __restrict__ Kb,
                                                const short* __restrict__ Vt,
                                                short* __restrict__ aob) {
  __shared__ short k_lds[2][64 * 64];
  __shared__ short v_lds[2][64 * 64];
  __shared__ short p_lds[8 * 16 * 64];
  const int tid = threadIdx.x, wid = tid >> 6, lane = tid & 63;
  const int lg = lane >> 4, lr = lane & 15;
  const int lin = blockIdx.x;
  const int swz = (lin & 7) * 64 + (lin >> 3);
  const int qt = swz & 15, bh = swz >> 4;   // XCD k owns bh [k*4, k*4+4)
  const int q0 = qt * 128 + wid * 16;
  const short* Qbh = Qb + (size_t)bh * 2048 * 64;
  const short* Kbh = Kb + (size_t)bh * 2048 * 64;
  const short* Vbh = Vt + (size_t)bh * 64 * 2048;
  const int rm = (lr >> 1) & 7;   // read-side swizzle mask (rows indexed by lr)

  // stage one KV tile (linear LDS dest + pre-swizzled global source)
  const int srow = tid >> 3;
  const int ssrc = ((tid & 7) ^ ((srow >> 1) & 7)) * 8;

  // loop-invariant p_lds write/read offsets
  int pw[4], pr[2];
  #pragma unroll
  for (int jt = 0; jt < 4; ++jt)
    pw[jt] = wid * 1024 + lr * 64 + (((jt * 2 + (lg >> 1)) ^ rm) * 8) + (lg & 1) * 4;
  #pragma unroll
  for (int kk = 0; kk < 2; ++kk)
    pr[kk] = wid * 1024 + lr * 64 + (((kk * 4 + lg) ^ rm) * 8);

  // all-ones bf16 fragment for the denominator MFMA (A=1 => D[i][q] = sum_k P[q][k])
  short8 ones;
  #pragma unroll
  for (int e = 0; e < 8; ++e) ones[e] = (short)0x3F80;

  // Q fragments hoisted; fold scale 0.125 * log2(e) (exp2-domain scores)
  short8 qf[2];
  #pragma unroll
  for (int kk = 0; kk < 2; ++kk) {
    qf[kk] = *(const short8*)(Qbh + (size_t)(q0 + lr) * 64 + kk * 32 + lg * 8);
    #pragma unroll
    for (int e = 0; e < 8; ++e) qf[kk][e] = f2b(b2f(qf[kk][e]) * 0.1803368801f);
  }

  f32x4 o[4], o_l;
  #pragma unroll
  for (int dt = 0; dt < 4; ++dt) o[dt] = (f32x4)0.0f;
  o_l = (f32x4)0.0f;
  float m_ = -__builtin_inff();

  // prologue: stage tile 0 into buf 0
  async_lds16(Kbh + (size_t)srow * 64 + ssrc, &k_lds[0][tid * 8]);
  async_lds16(Vbh + (size_t)srow * 2048 + 0 + ssrc, &v_lds[0][tid * 8]);
  asm volatile("s_waitcnt vmcnt(0)" ::: "memory");
  __syncthreads();

  for (int t = 0; t < 32; ++t) {
    const int cur = t & 1;
    // prefetch next tile into buf^1 (latency hides under this tile's compute)
    if (t + 1 < 32) {
      int kvn = (t + 1) * 64;
      async_lds16(Kbh + (size_t)(kvn + srow) * 64 + ssrc, &k_lds[cur ^ 1][tid * 8]);
      async_lds16(Vbh + (size_t)srow * 2048 + kvn + ssrc, &v_lds[cur ^ 1][tid * 8]);
    }

    // S^T = K Q^T : s[jt][r] = S[q=lr][k=jt*16+lg*4+r], log2 domain
    f32x4 s[4];
    #pragma unroll
    for (int jt = 0; jt < 4; ++jt) s[jt] = (f32x4)0.0f;
    #pragma unroll
    for (int jt = 0; jt < 4; ++jt)
      #pragma unroll
      for (int kk = 0; kk < 2; ++kk) {
        short8 kf = *(const short8*)&k_lds[cur][(jt * 16 + lr) * 64 +
                                               (((kk * 4 + lg) ^ rm) * 8)];
        s[jt] = MFMA16(kf, qf[kk], s[jt]);
      }

    // pmax: depth-4 tree (max3-fusable)
    float mj[4];
    #pragma unroll
    for (int jt = 0; jt < 4; ++jt)
      mj[jt] = fmaxf(fmaxf(s[jt][0], s[jt][1]), fmaxf(s[jt][2], s[jt][3]));
    float pmax = fmaxf(fmaxf(mj[0], mj[1]), fmaxf(mj[2], mj[3]));
    pmax = fmaxf(pmax, __shfl_xor(pmax, 16));
    pmax = fmaxf(pmax, __shfl_xor(pmax, 32));
    if (!__all(pmax - m_ <= 8.0f)) {      // defer-max: skip rescale if growth small
      float mn = fmaxf(m_, pmax);
      float corr = EXP2F(m_ - mn);        // exp2(-inf) = 0 handles t=0
      m_ = mn;
      #pragma unroll
      for (int dt = 0; dt < 4; ++dt)
        #pragma unroll
        for (int r = 0; r < 4; ++r) o[dt][r] *= corr;
      #pragma unroll
      for (int r = 0; r < 4; ++r) o_l[r] *= corr;
    }

    // fused exp -> pack -> P ds_write per jt (denominator now via ones-MFMA)
    #pragma unroll
    for (int jt = 0; jt < 4; ++jt) {
      short4v pv;
      pv[0] = f2b(EXP2F(s[jt][0] - m_));
      pv[1] = f2b(EXP2F(s[jt][1] - m_));
      pv[2] = f2b(EXP2F(s[jt][2] - m_));
      pv[3] = f2b(EXP2F(s[jt][3] - m_));
      *(short4v*)&p_lds[pw[jt]] = pv;
    }

    // O^T += V^T P^T ; o_l += 1^T P^T (row-sum of P via MFMA)
    #pragma unroll
    for (int kk = 0; kk < 2; ++kk) {
      short8 pa = *(const short8*)&p_lds[pr[kk]];
      o_l = MFMA16(ones, pa, o_l);
      #pragma unroll
      for (int dt = 0; dt < 4; ++dt) {
        short8 vb = *(const short8*)&v_lds[cur][(dt * 16 + lr) * 64 +
                                               (((kk * 4 + lg) ^ rm) * 8)];
        o[dt] = MFMA16(vb, pa, o[dt]);
      }
    }
    // single drain+barrier per tile (prefetch was issued ~2000 cyc ago)
    asm volatile("s_waitcnt vmcnt(0)" ::: "memory");
    __syncthreads();
  }

  // epilogue: out layout [b][n][h*64+d] bf16; n = q0+lr, packed 8B stores
  const int bb = bh >> 4, h = bh & 15;
  const float inv_l = __frcp_rn(o_l[0]);   // all 4 regs equal (ones rows)
  #pragma unroll
  for (int dt = 0; dt < 4; ++dt) {
    short4v ov;
    #pragma unroll
    for (int r = 0; r < 4; ++r) ov[r] = f2b(o[dt][r] * inv_l);
    *(short4v*)&aob[(size_t)(bb * 2048 + q0 + lr) * 1024 + h * 64 + dt * 16 + lg * 4] = ov;
  }
}

// ---------------- GEMM2: out = aob @ wprojT^T + b_proj (fp32 out) ----------------
// 64x128 tile, BK=64, 1D grid 512 (2 blocks/CU), XCD swizzle, T2 LDS swizzle.
__global__ __launch_bounds__(256, 2) void gemm_proj(const short* __restrict__ aob,
                                                    const short* __restrict__ wT,
                                                    const float* __restrict__ bias,
                                                    float* __restrict__ out) {
  __shared__ short lds_a[64 * 64];
  __shared__ short lds_b[128 * 64];
  const int tid = threadIdx.x, wid = tid >> 6, lane = tid & 63;
  const int lg = lane >> 4, lr = lane & 15;
  const int lin = blockIdx.x;
  const int swz = (lin & 7) * 64 + (lin >> 3);
  const int m0 = (swz & 63) * 64, n0 = (swz >> 6) * 128;  // same-B-panel per XCD
  const int mw = wid >> 1, nw = wid & 1;
  const int K = 1024;
  const int sm = lr & 7;

  f32x4 acc[2][4];
  #pragma unroll
  for (int i = 0; i < 2; ++i)
    #pragma unroll
    for (int j = 0; j < 4; ++j) acc[i][j] = (f32x4)0.0f;

  for (int k0 = 0; k0 < K; k0 += 64) {
    #pragma unroll
    for (int it = 0; it < 2; ++it) {                        // A: 64 x 64
      int chunk = it * 256 + tid;
      int row = chunk >> 3, kc = ((chunk & 7) ^ (row & 7)) * 8;
      async_lds16(aob + (size_t)(m0 + row) * K + k0 + kc, lds_a + chunk * 8);
    }
    #pragma unroll
    for (int it = 0; it < 4; ++it) {                        // B: 128 x 64
      int chunk = it * 256 + tid;
      int row = chunk >> 3, kc = ((chunk & 7) ^ (row & 7)) * 8;
      async_lds16(wT + (size_t)(n0 + row) * K + k0 + kc, lds_b + chunk * 8);
    }
    __syncthreads();
    #pragma unroll
    for (int kk = 0; kk < 2; ++kk) {
      short8 af[2], bfr[4];
      #pragma unroll
      for (int i = 0; i < 2; ++i)
        af[i] = *(const short8*)&lds_a[(mw * 32 + i * 16 + lr) * 64 +
                                       (((kk * 4 + lg) ^ sm) * 8)];
      #pragma unroll
      for (int j = 0; j < 4; ++j)
        bfr[j] = *(const short8*)&lds_b[(nw * 64 + j * 16 + lr) * 64 +
                                        (((kk * 4 + lg) ^ sm) * 8)];
      #pragma unroll
      for (int i = 0; i < 2; ++i)
        #pragma unroll
        for (int j = 0; j < 4; ++j) acc[i][j] = MFMA16(af[i], bfr[j], acc[i][j]);
    }
    __syncthreads();
  }

  #pragma unroll
  for (int i = 0; i < 2; ++i) {
    int gm = m0 + mw * 32 + i * 16 + lg * 4;
    #pragma unroll
    for (int j = 0; j < 4; ++j) {
      int gc = n0 + nw * 64 + j * 16 + lr;
      float bv = bias[gc];
      #pragma unroll
      for (int r = 0; r < 4; ++r)
        out[(size_t)(gm + r) * 1024 + gc] = acc[i][j][r] + bv;
    }
  }
}

// ---------------- launcher ----------------
extern "C" void kernel_launch(void* const* d_in, const int* in_sizes, int n_in,
                              void* d_out, int out_size, void* d_ws, size_t ws_size,
                              hipStream_t stream) {
  const float* x     = (const float*)d_in[0];  // [2,2048,1024]
  const float* wqkv  = (const float*)d_in[1];  // [1024,3072]
  const float* bqkv  = (const float*)d_in[2];  // [3072]
  const float* wproj = (const float*)d_in[3];  // [1024,1024]
  const float* bproj = (const float*)d_in[4];  // [1024]
  float* out = (float*)d_out;

  char* ws = (char*)d_ws;
  short* xb     = (short*)ws; ws += (size_t)4096 * 1024 * 2;  // 8 MB
  short* wqkvT  = (short*)ws; ws += (size_t)3072 * 1024 * 2;  // 6 MB
  short* wprojT = (short*)ws; ws += (size_t)1024 * 1024 * 2;  // 2 MB
  short* Qb     = (short*)ws; ws += (size_t)32 * 2048 * 64 * 2;  // 8 MB
  short* Kb     = (short*)ws; ws += (size_t)32 * 2048 * 64 * 2;  // 8 MB
  short* Vt     = (short*)ws; ws += (size_t)32 * 64 * 2048 * 2;  // 8 MB
  short* aob    = (short*)ws; ws += (size_t)4096 * 1024 * 2;     // 8 MB
  // total 48 MB workspace

  cast_f32_bf16<<<1024, 256, 0, stream>>>(x, xb, 4096 * 1024 / 4);
  transpose_cast<<<dim3(48, 16), 256, 0, stream>>>(wqkv, wqkvT, 1024, 3072);
  transpose_cast<<<dim3(16, 16), 256, 0, stream>>>(wproj, wprojT, 1024, 1024);
  gemm_qkv<<<768, 256, 0, stream>>>(xb, wqkvT, bqkv, Qb, Kb, Vt);
  attn_fwd<<<512, 512, 0, stream>>>(Qb, Kb, Vt, aob);
  gemm_proj<<<512, 256, 0, stream>>>(aob, wprojT, bproj, out);
}